// Round 9
// baseline (2495.458 us; speedup 1.0000x reference)
//
#include <hip/hip_runtime.h>
#include <hip/hip_bf16.h>
#include <math.h>

typedef __hip_bfloat16 bf16;
typedef unsigned long long u64;
using s8v = __attribute__((ext_vector_type(8))) short;
using f4v = __attribute__((ext_vector_type(4))) float;

#define B_   16
#define L_   96
#define NV   862
#define DM   512
#define NH   8
#define DH   64
#define KFL  5000
#define NBN  (B_*NV)   /* 13792 */
#define NVP  896
#define QKVW 1536      /* fused QKV row width */
#define L2P  128       /* padded row stride for xT/trend (K=96 -> 128) */

#define BAR()  __builtin_amdgcn_s_barrier()
#define SCB()  __builtin_amdgcn_sched_barrier(0)
#define VMW0() asm volatile("s_waitcnt vmcnt(0)" ::: "memory")
#define VMW4() asm volatile("s_waitcnt vmcnt(4)" ::: "memory")
#define VMW6() asm volatile("s_waitcnt vmcnt(6)" ::: "memory")
#define VMW8() asm volatile("s_waitcnt vmcnt(8)" ::: "memory")

__device__ __forceinline__ float tof(bf16 x)  { return __bfloat162float(x); }

/* linear-stride-64 LDS swizzled read index (paired with source-side swizzle) */
__device__ __forceinline__ int sxl(int r, int c) {
    return (r << 6) + ((c ^ (r & 7)) << 3);
}
/* P-tile stride-64 swizzle: XOR within 8-row stripe + rotate-2 for rows 8-15. */
__device__ __forceinline__ int px(int r, int k) {
    return (r << 6) + (((((k >> 3) ^ (r & 7)) + ((r & 8) >> 2)) & 7) << 3) + (k & 7);
}
__device__ __forceinline__ int pxc(int r, int c) {
    return (r << 6) + ((((c ^ (r & 7)) + ((r & 8) >> 2)) & 7) << 3);
}

/* async 16B global -> LDS (vmcnt-counted; LDS dest = wave-uniform base + lane*16) */
__device__ __forceinline__ void gl16(const bf16* g, bf16* l)
{
    __builtin_amdgcn_global_load_lds(
        (const __attribute__((address_space(1))) void*)g,
        (__attribute__((address_space(3))) void*)l, 16, 0, 0);
}

/* stage a 64x64 bf16 tile (256 threads): rows clamped to rmax, source column
 * pre-swizzled so linear LDS + sxl() reads line up. 2 VMEM instrs per wave. */
__device__ __forceinline__ void stage64(const bf16* __restrict__ src, int ld,
                                        int r0, int rmax, int k0, bf16* buf, int tid)
{
    #pragma unroll
    for (int i = 0; i < 2; i++) {
        int e = tid + i * 256;
        int r = e >> 3, c = e & 7;
        int gr = r0 + r; gr = gr > rmax ? rmax : gr;
        int gk = k0 + ((c ^ (r & 7)) << 3);
        gl16(src + (size_t)gr * ld + gk, buf + ((size_t)(e >> 6) << 9));
    }
}
/* 128x64 tile variant (256 threads); 4 VMEM instrs per wave */
__device__ __forceinline__ void stage128(const bf16* __restrict__ src, int ld,
                                         int r0, int rmax, int k0, bf16* buf, int tid)
{
    #pragma unroll
    for (int i = 0; i < 4; i++) {
        int e = tid + i * 256;
        int r = e >> 3, c = e & 7;
        int gr = r0 + r; gr = gr > rmax ? rmax : gr;
        int gk = k0 + ((c ^ (r & 7)) << 3);
        gl16(src + (size_t)gr * ld + gk, buf + ((size_t)(e >> 6) << 9));
    }
}
/* 256x64 tile variant (512 threads); 4 VMEM instrs per wave */
__device__ __forceinline__ void stage256w(const bf16* __restrict__ src, int ld,
                                          int r0, int rmax, int k0, bf16* buf, int tid)
{
    #pragma unroll
    for (int i = 0; i < 4; i++) {
        int e = tid + i * 512;
        int r = e >> 3, c = e & 7;
        int gr = r0 + r; gr = gr > rmax ? rmax : gr;
        int gk = k0 + ((c ^ (r & 7)) << 3);
        gl16(src + (size_t)gr * ld + gk, buf + ((size_t)(e >> 6) << 9));
    }
}

/* bijective XCD-aware block remap (m204): consecutive work chunks per XCD */
__device__ __forceinline__ int xcd_swz(int orig, int nwg)
{
    int q = nwg >> 3, r = nwg & 7;
    int xc = orig & 7, loc = orig >> 3;
    return (xc < r ? xc * (q + 1) : r * (q + 1) + (xc - r) * q) + loc;
}

// ---------------------------------------------------------------------------
__global__ void detect_k(const unsigned short* __restrict__ rw, int* __restrict__ flag)
{
    if (threadIdx.x == 0 && blockIdx.x == 0)
        *flag = (rw[0] == 0 && rw[2] == 0 && rw[4] == 0) ? 1 : 0;
}

// batched flat convert: 30 tensors, one launch
struct CB { const void* src[30]; bf16* dst[30]; int n[30]; int so[30]; };
__global__ __launch_bounds__(256)
void cvtb_k(CB cb, const int* __restrict__ flag)
{
    int t = blockIdx.y;
    int i = blockIdx.x * 256 + threadIdx.x;
    if (i >= cb.n[t]) return;
    int s = cb.so[t] + i;
    if (*flag) cb.dst[t][i] = __float2bfloat16(((const float*)cb.src[t])[s]);
    else       cb.dst[t][i] = ((const bf16*)cb.src[t])[s];
}

// batched transpose-convert: src[srcOff + k*N + n] -> dst[n*Kp + k]; zero-pads
// k in [K, Kp) so pipelined GEMMs can treat K as a multiple of 64
#define NWT 24
struct WD { const void* src; bf16* dst; int K, Kp, N; long srcOff; };
struct WTB { WD d[NWT]; };
__global__ __launch_bounds__(256)
void wtcb_k(WTB wb, const int* __restrict__ flag)
{
    __shared__ bf16 tile[32][33];
    WD dd = wb.d[blockIdx.z];
    int n0 = blockIdx.x * 32, k0 = blockIdx.y * 32;
    if (n0 >= dd.N || k0 >= dd.Kp) return;
    int tx = threadIdx.x & 31, ty = threadIdx.x >> 5;
    int f32 = *flag;
    #pragma unroll
    for (int r = 0; r < 4; r++) {
        int k = k0 + ty + r * 8, n = n0 + tx;
        bf16 v = __float2bfloat16(0.f);
        if (k < dd.K && n < dd.N)
            v = f32 ? __float2bfloat16(((const float*)dd.src)[dd.srcOff + (size_t)k * dd.N + n])
                    : ((const bf16*)dd.src)[dd.srcOff + (size_t)k * dd.N + n];
        tile[ty + r * 8][tx] = v;
    }
    __syncthreads();
    #pragma unroll
    for (int r = 0; r < 4; r++) {
        int n = n0 + ty + r * 8, k = k0 + tx;
        if (n < dd.N && k < dd.Kp) dd.dst[(size_t)n * dd.Kp + k] = tile[tx][ty + r * 8];
    }
}

// ---------------------------------------------------------------------------
// per-(b,h) V transpose from fused QKV
// ---------------------------------------------------------------------------
__global__ __launch_bounds__(256)
void vt_k(const bf16* __restrict__ qkv, bf16* __restrict__ Vt)
{
    __shared__ bf16 t[32][33];
    int bh = blockIdx.z;
    int n0 = blockIdx.x * 32, d0 = blockIdx.y * 32;
    int b = bh >> 3, h = bh & 7;
    int tx = threadIdx.x & 31, ty = threadIdx.x >> 5;
    #pragma unroll
    for (int r = 0; r < 4; r++) {
        int n = n0 + ty + r * 8, d = d0 + tx;
        bf16 v = __float2bfloat16(0.f);
        if (n < NV) v = qkv[(size_t)(b * NV + n) * QKVW + 1024 + h * DH + d];
        t[ty + r * 8][tx] = v;
    }
    __syncthreads();
    #pragma unroll
    for (int r = 0; r < 4; r++) {
        int d = d0 + ty + r * 8, n = n0 + tx;
        Vt[((size_t)bh * DH + d) * NVP + n] = t[tx][ty + r * 8];
    }
}

// ---------------------------------------------------------------------------
// RevIN + trend (xT/trend padded to stride L2P=128, cols 96..127 zero)
// ---------------------------------------------------------------------------
__global__ __launch_bounds__(128)
void revin_k(const void* __restrict__ x_enc, const bf16* __restrict__ rw,
             const bf16* __restrict__ rb, bf16* __restrict__ xT,
             bf16* __restrict__ trend, float* __restrict__ meanA,
             float* __restrict__ stdA, const int* __restrict__ flag)
{
    int row = blockIdx.x;
    int b = row / NV, n = row - b * NV;
    int tid = threadIdx.x;
    int f32 = *flag;
    __shared__ float xr[96];
    __shared__ float part[2][2];
    __shared__ float mv[2];
    float v = 0.f;
    if (tid < 96) {
        size_t idx = ((size_t)b * L_ + tid) * NV + n;
        v = f32 ? ((const float*)x_enc)[idx] : tof(((const bf16*)x_enc)[idx]);
    }
    float s = v, sq = v * v;
    #pragma unroll
    for (int off = 32; off; off >>= 1) {
        s  += __shfl_xor(s,  off, 64);
        sq += __shfl_xor(sq, off, 64);
    }
    int wid = tid >> 6;
    if ((tid & 63) == 0) { part[wid][0] = s; part[wid][1] = sq; }
    __syncthreads();
    if (tid == 0) {
        float S = part[0][0] + part[1][0], Q = part[0][1] + part[1][1];
        float m = S / 96.f;
        float var = fmaxf(Q / 96.f - m * m, 0.f);
        float st = sqrtf(var + 1e-5f);
        mv[0] = m; mv[1] = st;
        meanA[row] = m; stdA[row] = st;
    }
    __syncthreads();
    float m = mv[0], st = mv[1];
    const bf16 z16 = __float2bfloat16(0.f);
    if (tid < 96) {
        float xv = (v - m) / st * tof(rw[n]) + tof(rb[n]);
        xr[tid] = xv;
        xT[(size_t)row * L2P + tid] = __float2bfloat16(xv);
    } else {
        xT[(size_t)row * L2P + tid] = z16;
    }
    __syncthreads();
    if (tid < 96) {
        float acc = 0.f;
        #pragma unroll
        for (int d = -12; d <= 12; d++) {
            int k = tid + d;
            k = k < 0 ? 0 : (k > 95 ? 95 : k);
            acc += xr[k];
        }
        trend[(size_t)row * L2P + tid] = __float2bfloat16(acc * (1.f / 25.f));
    } else {
        trend[(size_t)row * L2P + tid] = z16;
    }
}

// ---------------------------------------------------------------------------
__global__ void myf_k(const bf16* __restrict__ yf_w, bf16* __restrict__ MyfT)
{
    int idx = blockIdx.x * 256 + threadIdx.x;
    if (idx >= 512 * L2P) return;
    int d = idx >> 7, l = idx & 127;
    const float invs = 0.10206207261596575f;
    float acc = 0.f;
    if (l < 96) {
        for (int f = 0; f < 25; f++) {
            float ang = (float)(f * l) / 48.0f;
            acc += cospif(ang) * tof(yf_w[f * 512 + d]);
            acc -= sinpif(ang) * tof(yf_w[(25 + f) * 512 + d]);
        }
        acc *= invs;
    }
    MyfT[(size_t)d * L2P + l] = __float2bfloat16(acc);
}

__global__ void ceff_k(const bf16* __restrict__ fc4_w, bf16* __restrict__ CeffT)
{
    int idx = blockIdx.x * 256 + threadIdx.x;
    if (idx >= 512 * 64) return;
    int d = idx >> 6, f = idx & 63;
    const float invs = 0.10206207261596575f;
    float acc = 0.f;
    if (f < 49) {
        for (int l = 0; l < 96; l++) {
            float coef;
            if (f == 0)       coef = 1.f;
            else if (f == 48) coef = (l & 1) ? -1.f : 1.f;
            else              coef = 2.f * cospif((float)(f * l) / 48.f);
            acc += coef * tof(fc4_w[l * 512 + d]);
        }
        acc *= invs;
    }
    CeffT[(size_t)d * 64 + f] = __float2bfloat16(acc);
}

// ---------------------------------------------------------------------------
// epilogue: act 0 none,1 relu,2 lrelu,3 gelu,4 noisy-gate,
//           5 bias - freq_gather(n), 6 bias + freq_gather(512+n)
// ---------------------------------------------------------------------------
__device__ __forceinline__ float epi(float v, int n, int m, int N, int act,
                                     const bf16* bias, const float* Res,
                                     const void* ft, const int* kf,
                                     const int* dflag)
{
    if (act >= 5) {
        v += tof(bias[n]);
        int b = m / NV, nv = m - b * NV;
        int gi = (act == 5) ? (kf[b] + n) % KFL : (kf[b] + 512 + n) % KFL;
        size_t gidx = (size_t)gi * NV + nv;
        float fv = (*dflag) ? ((const float*)ft)[gidx] : tof(((const bf16*)ft)[gidx]);
        return (act == 5) ? v - fv : v + fv;
    }
    if (act == 4) {
        float z = -(v + 0.01f);
        float sp = fmaxf(z, 0.f) + log1pf(expf(-fabsf(z)));
        return Res[(size_t)m * N + n] + tof(bias[n]) * (-sp);
    }
    if (bias) v += tof(bias[n]);
    if (Res)  v += Res[(size_t)m * N + n];
    if (act == 1)      v = fmaxf(v, 0.f);
    else if (act == 2) v = (v >= 0.f) ? v : 0.01f * v;
    else if (act == 3) v = 0.5f * v * (1.f + erff(v * 0.70710678118654752f));
    return v;
}

// ---------------------------------------------------------------------------
// 256x256 MFMA GEMM, 512 threads (8 waves), BK=64, counted-vmcnt double
// buffer, 128KB LDS. Register budget pinned EXPLICITLY: amdgpu_waves_per_eu
// (2,2) -> 512-VGPR pool / 2 waves = 256 VGPR/thread budget (need ~170:
// 128 acc + operands + addr). r7's __launch_bounds__(512,2) capped at 128
// (CUDA minBlocks semantics) and r8's bare (512) let the occupancy heuristic
// pick 100 -> both spilled (212MB scratch writes). This pins it.
// ---------------------------------------------------------------------------
__global__ __attribute__((amdgpu_flat_work_group_size(512, 512), amdgpu_waves_per_eu(2, 2)))
void gemm256(const bf16* __restrict__ A, int lda,
             const bf16* __restrict__ Wt, int ldb,
             const bf16* __restrict__ bias, const float* Res,
             float* C32, bf16* C16, int M, int N, int K, int act, int gx)
{
    __shared__ __align__(16) bf16 As[2][256 * 64];   // 32 KB x2
    __shared__ __align__(16) bf16 Bs[2][256 * 64];   // 32 KB x2
    int tid = threadIdx.x;
    int w = tid >> 6, lane = tid & 63;
    int lr = lane >> 4, lc = lane & 15;
    int nid = xcd_swz(blockIdx.x, gridDim.x);
    int bx = nid % gx, by = nid / gx;
    int row0 = by * 256, col0 = bx * 256;
    int mq = (w >> 1) * 64;      // 4 row-groups of 64
    int nq = (w & 1) * 128;      // 2 col-groups of 128
    f4v acc[4][8] = {};
    int nt = K >> 6;
    stage256w(A, lda, row0, M - 1, 0, As[0], tid);
    stage256w(Wt, ldb, col0, N - 1, 0, Bs[0], tid);
    if (nt > 1) {
        stage256w(A, lda, row0, M - 1, 64, As[1], tid);
        stage256w(Wt, ldb, col0, N - 1, 64, Bs[1], tid);
        VMW8();
    } else {
        VMW0();
    }
    BAR(); SCB();
    for (int t = 0; t < nt; t++) {
        int cur = t & 1;
        #pragma unroll
        for (int sub = 0; sub < 2; sub++) {
            int ck = sub * 4 + lr;
            s8v a[4];
            #pragma unroll
            for (int mt = 0; mt < 4; mt++) a[mt] = *(const s8v*)&As[cur][sxl(mq + mt * 16 + lc, ck)];
            #pragma unroll
            for (int jh = 0; jh < 2; jh++) {        // two half-chunks keep live B regs at 4
                s8v b[4];
                #pragma unroll
                for (int j = 0; j < 4; j++)
                    b[j] = *(const s8v*)&Bs[cur][sxl(nq + jh * 64 + j * 16 + lc, ck)];
                #pragma unroll
                for (int mt = 0; mt < 4; mt++)
                    #pragma unroll
                    for (int j = 0; j < 4; j++)
                        acc[mt][jh * 4 + j] = __builtin_amdgcn_mfma_f32_16x16x32_bf16(
                            a[mt], b[j], acc[mt][jh * 4 + j], 0, 0, 0);
            }
        }
        if (t + 1 < nt) {
            SCB(); BAR(); SCB();        // all waves done reading buf[cur]
            if (t + 2 < nt) {
                stage256w(A, lda, row0, M - 1, (t + 2) << 6, As[cur], tid);
                stage256w(Wt, ldb, col0, N - 1, (t + 2) << 6, Bs[cur], tid);
                VMW8();                 // t+1's loads complete; t+2's stay in flight
            } else {
                VMW0();
            }
            BAR(); SCB();
        }
    }
    #pragma unroll
    for (int mt = 0; mt < 4; mt++)
    #pragma unroll
    for (int j = 0; j < 8; j++) {
        #pragma unroll
        for (int r = 0; r < 4; r++) {
            int m = row0 + mq + mt * 16 + lr * 4 + r;
            int n = col0 + nq + j * 16 + lc;
            if (m >= M || n >= N) continue;
            float v = epi(acc[mt][j][r], n, m, N, act, bias, Res, nullptr, nullptr, nullptr);
            if (C32) C32[(size_t)m * N + n] = v;
            if (C16) C16[(size_t)m * N + n] = __float2bfloat16(v);
        }
    }
}

// ---------------------------------------------------------------------------
// counted-vmcnt pipelined 128x128 GEMM (r4 form, best-known for these shapes)
// ---------------------------------------------------------------------------
__global__ __launch_bounds__(256)
void gemm128c(const bf16* __restrict__ A, int lda,
              const bf16* __restrict__ Wt, int ldb,
              const bf16* __restrict__ bias, const float* Res,
              float* C32, bf16* C16, int M, int N, int K, int act, int gx)
{
    __shared__ __align__(16) bf16 As[2][128 * 64];
    __shared__ __align__(16) bf16 Bs[2][128 * 64];
    int tid = threadIdx.x;
    int w = tid >> 6, lane = tid & 63;
    int lr = lane >> 4, lc = lane & 15;
    int nid = xcd_swz(blockIdx.x, gridDim.x);
    int bx = nid % gx, by = nid / gx;
    int row0 = by * 128, col0 = bx * 128;
    int mq = (w >> 1) * 64, nq = (w & 1) * 64;
    f4v acc[4][4] = {};
    int nt = K >> 6;
    stage128(A, lda, row0, M - 1, 0, As[0], tid);
    stage128(Wt, ldb, col0, N - 1, 0, Bs[0], tid);
    if (nt > 1) {
        stage128(A, lda, row0, M - 1, 64, As[1], tid);
        stage128(Wt, ldb, col0, N - 1, 64, Bs[1], tid);
        VMW8();
    } else {
        VMW0();
    }
    BAR(); SCB();
    for (int t = 0; t < nt; t++) {
        int cur = t & 1;
        #pragma unroll
        for (int sub = 0; sub < 2; sub++) {
            int ck = sub * 4 + lr;
            s8v a[4], b[4];
            #pragma unroll
            for (int mt = 0; mt < 4; mt++) a[mt] = *(const s8v*)&As[cur][sxl(mq + mt * 16 + lc, ck)];
            #pragma unroll
            for (int j = 0; j < 4; j++) b[j] = *(const s8v*)&Bs[cur][sxl(nq + j * 16 + lc, ck)];
            #pragma unroll
            for (int mt = 0; mt < 4; mt++)
                #pragma unroll
                for (int j = 0; j < 4; j++)
                    acc[mt][j] = __builtin_amdgcn_mfma_f32_16x16x32_bf16(a[mt], b[j], acc[mt][j], 0, 0, 0);
        }
        if (t + 1 < nt) {
            SCB(); BAR(); SCB();
            if (t + 2 < nt) {
                stage128(A, lda, row0, M - 1, (t + 2) << 6, As[cur], tid);
                stage128(Wt, ldb, col0, N - 1, (t + 2) << 6, Bs[cur], tid);
                VMW8();
            } else {
                VMW0();
            }
            BAR(); SCB();
        }
    }
    #pragma unroll
    for (int mt = 0; mt < 4; mt++)
    #pragma unroll
    for (int j = 0; j < 4; j++) {
        #pragma unroll
        for (int r = 0; r < 4; r++) {
            int m = row0 + mq + mt * 16 + lr * 4 + r;
            int n = col0 + nq + j * 16 + lc;
            if (m >= M || n >= N) continue;
            float v = epi(acc[mt][j][r], n, m, N, act, bias, Res, nullptr, nullptr, nullptr);
            if (C32) C32[(size_t)m * N + n] = v;
            if (C16) C16[(size_t)m * N + n] = __float2bfloat16(v);
        }
    }
}

// ---------------------------------------------------------------------------
// counted-vmcnt pipelined 64x128 GEMM (r4 form)
// ---------------------------------------------------------------------------
__global__ __launch_bounds__(256)
void gemm64c(const bf16* __restrict__ A, int lda,
             const bf16* __restrict__ Wt, int ldb,
             const bf16* __restrict__ bias, const float* Res,
             float* C32, bf16* C16, int M, int N, int K, int act,
             const void* ft, const int* kf, const int* dflag, int gx)
{
    __shared__ __align__(16) bf16 As[2][64 * 64];
    __shared__ __align__(16) bf16 Bs[2][128 * 64];
    int tid = threadIdx.x;
    int w = tid >> 6, lane = tid & 63;
    int lr = lane >> 4, lc = lane & 15;
    int nid = xcd_swz(blockIdx.x, gridDim.x);
    int bx = nid % gx, by = nid / gx;
    int row0 = by * 64, col0 = bx * 128;
    int mq = (w >> 1) * 32, nq = (w & 1) * 64;
    f4v acc[2][4] = {};
    int nt = K >> 6;
    stage64(A, lda, row0, M - 1, 0, As[0], tid);
    stage128(Wt, ldb, col0, N - 1, 0, Bs[0], tid);
    if (nt > 1) {
        stage64(A, lda, row0, M - 1, 64, As[1], tid);
        stage128(Wt, ldb, col0, N - 1, 64, Bs[1], tid);
        VMW6();
    } else {
        VMW0();
    }
    BAR(); SCB();
    for (int t = 0; t < nt; t++) {
        int cur = t & 1;
        #pragma unroll
        for (int sub = 0; sub < 2; sub++) {
            int ck = sub * 4 + lr;
            s8v a[2], b[4];
            #pragma unroll
            for (int mt = 0; mt < 2; mt++) a[mt] = *(const s8v*)&As[cur][sxl(mq + mt * 16 + lc, ck)];
            #pragma unroll
            for (int j = 0; j < 4; j++) b[j] = *(const s8v*)&Bs[cur][sxl(nq + j * 16 + lc, ck)];
            #pragma unroll
            for (int mt = 0; mt < 2; mt++)
                #pragma unroll
                for (int j = 0; j < 4; j++)
                    acc[mt][j] = __builtin_amdgcn_mfma_f32_16x16x32_bf16(a[mt], b[j], acc[mt][j], 0, 0, 0);
        }
        if (t + 1 < nt) {
            SCB(); BAR(); SCB();
            if (t + 2 < nt) {
                stage64(A, lda, row0, M - 1, (t + 2) << 6, As[cur], tid);
                stage128(Wt, ldb, col0, N - 1, (t + 2) << 6, Bs[cur], tid);
                VMW6();
            } else {
                VMW0();
            }
            BAR(); SCB();
        }
    }
    #pragma unroll
    for (int mt = 0; mt < 2; mt++)
    #pragma unroll
    for (int j = 0; j < 4; j++) {
        #pragma unroll
        for (int r = 0; r < 4; r++) {
            int m = row0 + mq + mt * 16 + lr * 4 + r;
            int n = col0 + nq + j * 16 + lc;
            if (m >= M || n >= N) continue;
            float v = epi(acc[mt][j][r], n, m, N, act, bias, Res, ft, kf, dflag);
            if (C32) C32[(size_t)m * N + n] = v;
            if (C16) C16[(size_t)m * N + n] = __float2bfloat16(v);
        }
    }
}

// ---------------------------------------------------------------------------
// merged output GEMMs (counted pipeline, r4 form): z in {0:dec, 1:x_time, 2:x_fre}
// ---------------------------------------------------------------------------
__global__ __launch_bounds__(256)
void outg_mfma(const bf16* __restrict__ xb16, const bf16* __restrict__ xfre16,
               const bf16* __restrict__ fcoT, const bf16* __restrict__ fc3T,
               const bf16* __restrict__ fc5T, const bf16* __restrict__ fcob,
               const bf16* __restrict__ fc3b, const bf16* __restrict__ fc5b,
               const bf16* __restrict__ rw, const bf16* __restrict__ rb,
               const float* __restrict__ meanA, const float* __restrict__ stdA,
               void* __restrict__ outv, const int* __restrict__ flag)
{
    __shared__ __align__(16) bf16 As[2][64 * 64];
    __shared__ __align__(16) bf16 Bs[2][64 * 64];
    const int M = NBN, N = 96;
    const size_t OSZ = (size_t)B_ * L_ * NV;
    int z = blockIdx.z;
    const bf16 *A1, *W1, *A2 = nullptr, *W2 = nullptr, *bias;
    int ldb; size_t obase;
    if (z == 0) { A1 = xb16; W1 = fcoT; A2 = xfre16; W2 = fcoT + 512; ldb = 1024; bias = fcob; obase = 0; }
    else if (z == 1) { A1 = xb16; W1 = fc3T; ldb = 512; bias = fc3b; obase = OSZ; }
    else { A1 = xfre16; W1 = fc5T; ldb = 512; bias = fc5b; obase = 2 * OSZ; }
    int tid = threadIdx.x;
    int w = tid >> 6, lane = tid & 63;
    int lr = lane >> 4, lc = lane & 15;
    int row0 = blockIdx.y * 64, col0 = blockIdx.x * 64;
    int mq = (w >> 1) * 32, nq = (w & 1) * 32;
    int f32o = *flag;
    f4v acc[2][2] = {};
    int nt = (z == 0) ? 16 : 8;       // 8 K-steps per 512-wide part
    stage64(A1, 512, row0, M - 1, 0, As[0], tid);
    stage64(W1, ldb, col0, N - 1, 0, Bs[0], tid);
    stage64(A1, 512, row0, M - 1, 64, As[1], tid);
    stage64(W1, ldb, col0, N - 1, 64, Bs[1], tid);
    VMW4();
    BAR(); SCB();
    for (int t = 0; t < nt; t++) {
        int cur = t & 1;
        #pragma unroll
        for (int sub = 0; sub < 2; sub++) {
            int ck = sub * 4 + lr;
            s8v a0 = *(const s8v*)&As[cur][sxl(mq + lc, ck)];
            s8v a1 = *(const s8v*)&As[cur][sxl(mq + 16 + lc, ck)];
            s8v b0 = *(const s8v*)&Bs[cur][sxl(nq + lc, ck)];
            s8v b1 = *(const s8v*)&Bs[cur][sxl(nq + 16 + lc, ck)];
            acc[0][0] = __builtin_amdgcn_mfma_f32_16x16x32_bf16(a0, b0, acc[0][0], 0, 0, 0);
            acc[0][1] = __builtin_amdgcn_mfma_f32_16x16x32_bf16(a0, b1, acc[0][1], 0, 0, 0);
            acc[1][0] = __builtin_amdgcn_mfma_f32_16x16x32_bf16(a1, b0, acc[1][0], 0, 0, 0);
            acc[1][1] = __builtin_amdgcn_mfma_f32_16x16x32_bf16(a1, b1, acc[1][1], 0, 0, 0);
        }
        if (t + 1 < nt) {
            SCB(); BAR(); SCB();
            if (t + 2 < nt) {
                int tn = t + 2;
                const bf16* Ax = (z == 0 && tn >= 8) ? A2 : A1;
                const bf16* Wx = (z == 0 && tn >= 8) ? W2 : W1;
                stage64(Ax, 512, row0, M - 1, (tn & 7) << 6, As[cur], tid);
                stage64(Wx, ldb, col0, N - 1, (tn & 7) << 6, Bs[cur], tid);
                VMW4();
            } else {
                VMW0();
            }
            BAR(); SCB();
        }
    }
    #pragma unroll
    for (int mt = 0; mt < 2; mt++)
    #pragma unroll
    for (int j = 0; j < 2; j++) {
        #pragma unroll
        for (int r = 0; r < 4; r++) {
            int m = row0 + mq + mt * 16 + lr * 4 + r;
            int c = col0 + nq + j * 16 + lc;
            if (m >= M || c >= N) continue;
            int b = m / NV, n = m - b * NV;
            float v = acc[mt][j][r] + tof(bias[c]);
            v = (v - tof(rb[n])) / (tof(rw[n]) + 1e-10f) * stdA[m] + meanA[m];
            size_t oidx = obase + ((size_t)b * L_ + c) * NV + n;
            if (f32o) ((float*)outv)[oidx] = v;
            else      ((bf16*)outv)[oidx] = __float2bfloat16(v);
        }
    }
}

// ---------------------------------------------------------------------------
// Gating -> 64-bit mask words (xe cached in registers: one global read pass)
// ---------------------------------------------------------------------------
__global__ __launch_bounds__(256)
void gating_k(const float* __restrict__ xe, u64* __restrict__ mask64)
{
    int row = blockIdx.x;
    int i = row % NV;
    int tid = threadIdx.x;
    size_t base = (size_t)row * NV;
    float vals[4];
    int cnt = 0;
    float mn = INFINITY, mx = -INFINITY;
    for (int j = tid; j < NV; j += 256) {
        float e = xe[base + j];
        vals[cnt++] = e;
        mn = fminf(mn, e);
        mx = fmaxf(mx, e);
    }
    #pragma unroll
    for (int off = 32; off; off >>= 1) {
        mn = fminf(mn, __shfl_xor(mn, off, 64));
        mx = fmaxf(mx, __shfl_xor(mx, off, 64));
    }
    __shared__ float smn[4], smx[4], fin[2];
    int w = tid >> 6, lane = tid & 63;
    if (lane == 0) { smn[w] = mn; smx[w] = mx; }
    __syncthreads();
    if (tid == 0) {
        float a = fminf(fminf(smn[0], smn[1]), fminf(smn[2], smn[3]));
        float c = fmaxf(fmaxf(smx[0], smx[1]), fmaxf(smx[2], smx[3]));
        fin[0] = a;
        fin[1] = 1.f / (c - a + 1e-6f);
    }
    __syncthreads();
    float a = fin[0], inv = fin[1];
    cnt = 0;
    for (int t = w; t < 14; t += 4) {
        int j = t * 64 + lane;            // == tid + 256*cnt
        bool masked = true;
        if (j < NV) {
            float lg = (vals[cnt++] - a) * inv + ((j == i) ? 1.f : 0.f);
            masked = (lg < 0.5f);
        }
        u64 word = __ballot(masked);
        if (lane == 0) mask64[(size_t)row * 16 + t] = word;
    }
}

// ---------------------------------------------------------------------------
__global__ __launch_bounds__(256)
void ln_k(const float* __restrict__ X, const bf16* __restrict__ g,
          const bf16* __restrict__ bta, float* __restrict__ Y32,
          bf16* __restrict__ Y16)
{
    int row = blockIdx.x;
    int tid = threadIdx.x;
    size_t base = (size_t)row * DM;
    float v0 = X[base + tid], v1 = X[base + tid + 256];
    float s = v0 + v1, sq = v0 * v0 + v1 * v1;
    #pragma unroll
    for (int off = 32; off; off >>= 1) {
        s  += __shfl_xor(s,  off, 64);
        sq += __shfl_xor(sq, off, 64);
    }
    __shared__ float ps[4], pq[4], mv[2];
    int wid = tid >> 6;
    if ((tid & 63) == 0) { ps[wid] = s; pq[wid] = sq; }
    __syncthreads();
    if (tid == 0) {
        float S = ps[0] + ps[1] + ps[2] + ps[3];
        float Q = pq[0] + pq[1] + pq[2] + pq[3];
        float m = S / 512.f;
        float var = fmaxf(Q / 512.f - m * m, 0.f);
        mv[0] = m;
        mv[1] = rsqrtf(var + 1e-5f);
    }
    __syncthreads();
    float m = mv[0], r = mv[1];
    float o0 = (v0 - m) * r * tof(g[tid])       + tof(bta[tid]);
    float o1 = (v1 - m) * r * tof(g[tid + 256]) + tof(bta[tid + 256]);
    if (Y32) { Y32[base + tid] = o0; Y32[base + tid + 256] = o1; }
    if (Y16) { Y16[base + tid] = __float2bfloat16(o0);
               Y16[base + tid + 256] = __float2bfloat16(o1); }
}

// ---------------------------------------------------------------------------
// Double LayerNorm (layer-2 second LN fused with final norm): z=LN(LN(x)g1+b1)g2+b2
// ---------------------------------------------------------------------------
__global__ __launch_bounds__(256)
void ln2x_k(const float* __restrict__ X, const bf16* __restrict__ g1,
            const bf16* __restrict__ b1, const bf16* __restrict__ g2,
            const bf16* __restrict__ b2, bf16* __restrict__ Y16)
{
    int row = blockIdx.x;
    int tid = threadIdx.x;
    size_t base = (size_t)row * DM;
    float v0 = X[base + tid], v1 = X[base + tid + 256];
    __shared__ float ps[4], pq[4], mv[2];
    int wid = tid >> 6;
    // pass 1
    {
        float s = v0 + v1, sq = v0 * v0 + v1 * v1;
        #pragma unroll
        for (int off = 32; off; off >>= 1) {
            s  += __shfl_xor(s,  off, 64);
            sq += __shfl_xor(sq, off, 64);
        }
        if ((tid & 63) == 0) { ps[wid] = s; pq[wid] = sq; }
        __syncthreads();
        if (tid == 0) {
            float S = ps[0] + ps[1] + ps[2] + ps[3];
            float Q = pq[0] + pq[1] + pq[2] + pq[3];
            float m = S / 512.f;
            float var = fmaxf(Q / 512.f - m * m, 0.f);
            mv[0] = m; mv[1] = rsqrtf(var + 1e-5f);
        }
        __syncthreads();
    }
    float m1 = mv[0], r1 = mv[1];
    float y0 = (v0 - m1) * r1 * tof(g1[tid])       + tof(b1[tid]);
    float y1 = (v1 - m1) * r1 * tof(g1[tid + 256]) + tof(b1[tid + 256]);
    __syncthreads();
    // pass 2
    {
        float s = y0 + y1, sq = y0 * y0 + y1 * y1;
        #pragma unroll
        for (int off = 32; off; off >>= 1) {
            s  += __shfl_xor(s,  off, 64);
            sq += __shfl_xor(sq, off, 64);
        }
        if ((tid & 63) == 0) { ps[wid] = s; pq[wid] = sq; }
        __syncthreads();
        if (tid == 0) {
            float S = ps[0] + ps[1] + ps[2] + ps[3];
            float Q = pq[0] + pq[1] + pq[2] + pq[3];
            float m = S / 512.f;
            float var = fmaxf(Q / 512.f - m * m, 0.f);
            mv[0] = m; mv[1] = rsqrtf(var + 1e-5f);
        }
        __syncthreads();
    }
    float m2 = mv[0], r2 = mv[1];
    Y16[base + tid]       = __float2bfloat16((y0 - m2) * r2 * tof(g2[tid])       + tof(b2[tid]));
    Y16[base + tid + 256] = __float2bfloat16((y1 - m2) * r2 * tof(g2[tid + 256]) + tof(b2[tid + 256]));
}

// ---------------------------------------------------------------------------
// Flash MFMA attention v7 (r4 form): LDS-staged K/V via global_load_lds +
// counted-vmcnt double buffer, conflict-free stride-64 layout, px/pxc P-tile.
// ---------------------------------------------------------------------------
__global__ __launch_bounds__(256)
void attn_k(const bf16* __restrict__ qkv, const bf16* __restrict__ Vt,
            const u64* __restrict__ mask64, bf16* __restrict__ O)
{
    __shared__ __align__(16) bf16 Ks[2][64 * 64];
    __shared__ __align__(16) bf16 Vs[2][64 * 64];
    __shared__ bf16 Pt[4][16 * 64];
    int bid = blockIdx.x;
    int bh = bid & 127;                 // B*NH = 128, fastest -> same XCD per (b,h)
    int q0 = (bid >> 7) * 64;
    int b = bh >> 3, h = bh & 7;
    int tid = threadIdx.x;
    int w = tid >> 6, lane = tid & 63;
    int lr = lane >> 4, lc = lane & 15;
    size_t hb = (size_t)h * DH;
    int qw = q0 + w * 16;
    const float C = 0.18033688011112042f;   // 0.125 * log2(e)

    s8v qf[2];
    #pragma unroll
    for (int sub = 0; sub < 2; sub++) {
        int gq = qw + lc;
        uint4 v = make_uint4(0, 0, 0, 0);
        if (gq < NV)
            v = *(const uint4*)(qkv + ((size_t)(b * NV + gq)) * QKVW + hb + sub * 32 + lr * 8);
        qf[sub] = *(s8v*)&v;
    }

    const bf16* kbase = qkv + (size_t)b * NV * QKVW + 512 + hb;  // row = key, 64 cols
    const bf16* vbase = Vt + (size_t)bh * DH * NVP;              // row = d, NVP cols

    float lsum[4] = {0.f, 0.f, 0.f, 0.f};
    f4v oacc[4] = {};
    const int NT = 14;

    // prologue: stage tiles 0 and 1 (4 VMEM/wave each)
    stage64(kbase, QKVW, 0, NV - 1, 0, Ks[0], tid);
    stage64(vbase, NVP, 0, DH - 1, 0, Vs[0], tid);
    stage64(kbase, QKVW, 64, NV - 1, 0, Ks[1], tid);
    stage64(vbase, NVP, 0, DH - 1, 64, Vs[1], tid);
    VMW4();                             // tile 0 complete; tile 1 in flight
    BAR(); SCB();

    for (int t = 0; t < NT; t++) {
        int cur = t & 1;
        // ---- QK^T from LDS (conflict-free sxl layout) ----
        f4v s[4];
        __builtin_amdgcn_s_setprio(1);
        #pragma unroll
        for (int nt = 0; nt < 4; nt++) {
            f4v sacc = {0.f, 0.f, 0.f, 0.f};
            #pragma unroll
            for (int sub = 0; sub < 2; sub++) {
                s8v bb = *(const s8v*)&Ks[cur][sxl(nt * 16 + lc, sub * 4 + lr)];
                sacc = __builtin_amdgcn_mfma_f32_16x16x32_bf16(qf[sub], bb, sacc, 0, 0, 0);
            }
            s[nt] = sacc;
        }
        __builtin_amdgcn_s_setprio(0);
        // ---- P = exp2(s*C), masked via per-row global mask word ----
        #pragma unroll
        for (int r = 0; r < 4; r++) {
            int gq = qw + lr * 4 + r;
            u64 wd = (gq < NV) ? mask64[(size_t)(b * NV + gq) * 16 + t] : ~0ull;
            #pragma unroll
            for (int nt = 0; nt < 4; nt++) {
                float p = ((wd >> (nt * 16 + lc)) & 1) ? 0.f : exp2f(s[nt][r] * C);
                Pt[w][px(lr * 4 + r, nt * 16 + lc)] = __float2bfloat16(p);
                lsum[r] += p;
            }
        }
        // ---- P @ V from LDS (Pt wave-private, RAW via lgkmcnt) ----
        #pragma unroll
        for (int sub = 0; sub < 2; sub++) {
            s8v pa = *(const s8v*)&Pt[w][pxc(lc, sub * 4 + lr)];
            __builtin_amdgcn_s_setprio(1);
            #pragma unroll
            for (int dt = 0; dt < 4; dt++) {
                s8v vv = *(const s8v*)&Vs[cur][sxl(dt * 16 + lc, sub * 4 + lr)];
                oacc[dt] = __builtin_amdgcn_mfma_f32_16x16x32_bf16(pa, vv, oacc[dt], 0, 0, 0);
            }
            __builtin_amdgcn_s_setprio(0);
        }
        if (t + 1 < NT) {
            SCB(); BAR(); SCB();        // all waves done reading buf[cur]
            if (t + 2 < NT) {
                int j2 = (t + 2) * 64;
                stage64(kbase, QKVW, j2, NV - 1, 0, Ks[cur], tid);
                stage64(vbase, NVP, 0, DH - 1, j2, Vs[cur], tid);
                VMW4();                 // t+1 complete; t+2 in flight
            } else {
                VMW0();
            }
            BAR(); SCB();
        }
    }
    // one deferred row-sum reduction over the 16 lanes sharing each row
    #pragma unroll
    for (int r = 0; r < 4; r++) {
        #pragma unroll
        for (int o2 = 1; o2 < 16; o2 <<= 1) lsum[r] += __shfl_xor(lsum[r], o2, 64);
    }
    #pragma unroll
    for (int r = 0; r < 4; r++) {
        int gq = qw + lr * 4 + r;
        if (gq >= NV) continue;
        float linv = 1.f / fmaxf(lsum[r], 1e-30f);
        #pragma unroll
        for (int dt = 0; dt < 4; dt++)
            O[((size_t)(b * NV + gq)) * DM + hb + dt * 16 + lc] =
                __float2bfloat16(oacc[dt][r] * linv);
    }
}

// ---------------------------------------------------------------------------
static void G256(hipStream_t s, const bf16* A, int lda, const bf16* Wt, int ldb,
                 const bf16* bias, const float* Res, float* C32, bf16* C16,
                 int M, int N, int K, int act)
{
    int gx = (N + 255) / 256, gy = (M + 255) / 256;
    gemm256<<<dim3(gx * gy), 512, 0, s>>>(A, lda, Wt, ldb, bias, Res, C32, C16,
                                          M, N, K, act, gx);
}
static void G1(hipStream_t s, const bf16* A, int lda, const bf16* Wt, int ldb,
               const bf16* bias, const float* Res, float* C32, bf16* C16,
               int M, int N, int K, int act)
{
    int gx = (N + 127) / 128, gy = (M + 127) / 128;
    gemm128c<<<dim3(gx * gy), 256, 0, s>>>(A, lda, Wt, ldb, bias, Res, C32, C16, M, N, K, act, gx);
}
static void G64(hipStream_t s, const bf16* A, int lda, const bf16* Wt, int ldb,
                const bf16* bias, const float* Res, float* C32, bf16* C16,
                int M, int N, int K, int act,
                const void* ft = nullptr, const int* kf = nullptr, const int* df = nullptr)
{
    int gx = (N + 127) / 128, gy = (M + 63) / 64;
    gemm64c<<<dim3(gx * gy), 256, 0, s>>>(A, lda, Wt, ldb, bias, Res, C32, C16, M, N, K, act, ft, kf, df, gx);
}

enum { I_XENC = 0, I_GNOISE, I_RW, I_RB, I_FC2W, I_FC2B, I_FC3W, I_FC3B,
       I_FC4W, I_FC4B, I_FC5W, I_FC5B, I_TCW1, I_TCW2, I_TNW1, I_TNW2,
       I_LTW1, I_LTB1, I_LTW2, I_LTB2, I_YFW, I_YFB, I_LSW1, I_LSB1,
       I_LSW2, I_LSB2, I_FCOW, I_FCOB, I_FT, I_EWQ, I_EBQ, I_EWK, I_EBK,
       I_EWV, I_EBV, I_EWO, I_EBO, I_C1W, I_C1B, I_C2W, I_C2B,
       I_G1, I_BE1, I_G2, I_BE2, I_NG, I_NB };

extern "C" void kernel_launch(void* const* d_in, const int* in_sizes, int n_in,
                              void* d_out, int out_size, void* d_ws, size_t ws_size,
                              hipStream_t stream)
{
    const int* bkey = (const int*)d_in[47];
    (void)ws_size; (void)in_sizes; (void)n_in; (void)out_size;

    // ---- arena (~190 MB) ----
    float* ws = (float*)d_ws;
    size_t off = 0;
    auto alloc = [&](size_t nf) { nf = (nf + 3) & ~(size_t)3; float* p = ws + off; off += nf; return p; };
    auto balloc = [&](size_t nb) { return (bf16*)alloc((nb + 1) / 2); };
    int*  flag  = (int*)alloc(16);
    bf16* gnoise = balloc(862); bf16* rw = balloc(862); bf16* rb = balloc(862);
    bf16* fc2b = balloc(512);  bf16* fc3b = balloc(96);
    bf16* fc4w_c = balloc(49152); bf16* fc4b = balloc(512); bf16* fc5b = balloc(96);
    bf16* ltb1 = balloc(512);  bf16* ltb2 = balloc(512);
    bf16* yfw_c = balloc(25600); bf16* yfb = balloc(512);
    bf16* lsb1 = balloc(512);  bf16* lsb2 = balloc(512);
    bf16* fcob = balloc(96);
    bf16* qkvb = balloc(2 * QKVW);
    bf16* ebo = balloc(1024);  bf16* c1b = balloc(2048); bf16* c2b = balloc(1024);
    bf16* g1v = balloc(1024);  bf16* be1v = balloc(1024);
    bf16* g2v = balloc(1024);  bf16* be2v = balloc(1024);
    bf16* ngv = balloc(512);   bf16* nbv = balloc(512);
    bf16* fc2wT = balloc(512 * L2P);  bf16* fc3wT = balloc(49152); bf16* fc5wT = balloc(49152);
    bf16* lt1T = balloc(512 * L2P);   bf16* lt2T = balloc(262144);
    bf16* ls1T = balloc(262144);  bf16* ls2T = balloc(262144);
    bf16* fcoT = balloc(98304);
    bf16* tc2T = balloc(220672);  bf16* tn2T = balloc(220672);
    bf16* gate1w = balloc(262144);
    bf16* qkvw = balloc(2 * QKVW * 512);
    bf16* woT = balloc(524288);
    bf16* c1T = balloc(1048576);  bf16* c2T = balloc(1048576);
    bf16* xT    = balloc((size_t)NBN * L2P);
    bf16* trend = balloc((size_t)NBN * L2P);
    float* meanA = alloc(13824);
    float* stdA  = alloc(13824);
    bf16* MyfT  = balloc(512 * L2P);
    bf16* CeffT = balloc(512 * 64);
    bf16* y49   = balloc((size_t)NBN * 64);
    float* xb32 = alloc((size_t)NBN * 512);
    bf16* xb16  = balloc((size_t)NBN * 512);
    bf16* xfre16 = balloc((size_t)NBN * 512);
    bf16* tmp16 = balloc((size_t)NBN * 1024);   // FF hidden / gate1 / Vt / freq scratch
    float* fbuf = alloc((size_t)NBN * 512);
    float* gbuf = alloc((size_t)NBN * 1024);    // xe fp32 / yA / qkv16+O16
    u64* mask64 = (u64*)alloc((size_t)NBN * 32);

    float* xe = gbuf;
    bf16* yA  = (bf16*)gbuf;
    bf16* qkv16 = (bf16*)gbuf;                  // [NBN][1536]
    bf16* O16 = qkv16 + (size_t)NBN * QKVW;     // [NBN][512]
    bf16* Vt  = tmp16;                          // [128][64][896]

    detect_k<<<1, 64, 0, stream>>>((const unsigned short*)d_in[I_RW], flag);

    // ---- batched flat conversions ----
    {
        CB cb;
        int k = 0;
        auto add = [&](int idx, bf16* dst, int n, int so) {
            cb.src[k] = d_in[idx]; cb.dst[k] = dst; cb.n[k] = n; cb.so[k] = so; k++;
        };
        add(I_GNOISE, gnoise, 862, 0); add(I_RW, rw, 862, 0); add(I_RB, rb, 862, 0);
        add(I_FC2B, fc2b, 512, 0); add(I_FC3B, fc3b, 96, 0);
        add(I_FC4W, fc4w_c, 49152, 0); add(I_FC4B, fc4b, 512, 0); add(I_FC5B, fc5b, 96, 0);
        add(I_LTB1, ltb1, 512, 0); add(I_LTB2, ltb2, 512, 0);
        add(I_YFW, yfw_c, 25600, 0); add(I_YFB, yfb, 512, 0);
        add(I_LSB1, lsb1, 512, 0); add(I_LSB2, lsb2, 512, 0);
        add(I_FCOB, fcob, 96, 0);
        add(I_EBQ, qkvb + 0, 512, 0);          add(I_EBQ, qkvb + QKVW, 512, 512);
        add(I_EBK, qkvb + 512, 512, 0);        add(I_EBK, qkvb + QKVW + 512, 512, 512);
        add(I_EBV, qkvb + 1024, 512, 0);       add(I_EBV, qkvb + QKVW + 1024, 512, 512);
        add(I_EBO, ebo, 1024, 0); add(I_C1B, c1b, 2048, 0); add(I_C2B, c2b, 1024, 0);
        add(I_G1, g1v, 1024, 0); add(I_BE1, be1v, 1024, 0);
        add(I_G2, g2v, 1024, 0); add(I_BE2, be2v, 1024, 0);
        add(I_NG, ngv, 512, 0); add(I_NB, nbv, 512, 0);
        cvtb_k<<<dim3(192, 30), 256, 0, stream>>>(cb, flag);
    }

    // ---- batched weight transposes (24 entries, one launch; Kp-padded) ----
    {
        WTB wb;
        int k = 0;
        auto add = [&](int idx, bf16* dst, int K, int Kp, int N, long soff) {
            wb.d[k].src = d_in[idx]; wb.d[k].dst = dst;
            wb.d[k].K = K; wb.d[k].Kp = Kp; wb.d[k].N = N; wb.d[k].srcOff = soff; k++;
        };
        add(I_FC2W, fc2wT, 96, L2P, 512, 0);
        add(I_FC3W, fc3wT, 512, 512, 96, 0);
        add(I_FC5W, fc5wT, 512, 512, 96, 0);
        add(I_LTW1, lt1T, 96, L2P, 512, 0);
        add(I_LTW2, lt2T, 512, 512, 512, 0);
        add(I_LSW1, ls1T, 512, 512, 512, 0);
        add(I_LSW2, ls2T, 512, 512, 512, 0);
        add(I_FCOW, fcoT, 1024, 1024, 96, 0);
        add(I_TCW2, tc2T, 256, 256, 862, 0);
        add(I_TNW2, tn2T, 256, 256, 862, 0);
        add(I_TCW1, gate1w, 512, 512, 256, 0);
        add(I_TNW1, gate1w + 256 * 512, 512, 512, 256, 0);
        for (int l = 0; l < 2; l++) {
            add(I_EWO, woT + (size_t)l * 262144, 512, 512, 512, (long)l * 262144);
            add(I_C1W, c1T + (size_t)l * 524288, 512, 512, 1024, (long)l * 524288);
            add(I_C2W, c2T + (size_t)l * 524288, 1024, 1024, 512, (long)l * 524288);
            add(I_EWQ, qkvw + (size_t)l * 786432 + 0,      512, 512, 512, (long)l * 262144);
            add(I_EWK, qkvw + (size_t)l * 786432 + 262144, 512, 512, 512, (long)l * 262144);
            add(I_EWV, qkvw + (size_t)l * 786432 + 524288, 512, 512, 512, (long)l * 262144);
        }
        wtcb_k<<<dim3(32, 32, NWT), 256, 0, stream>>>(wb, flag);
    }

    // ---- RevIN + trend; DFT/IDFT folds ----
    revin_k<<<NBN, 128, 0, stream>>>(d_in[I_XENC], rw, rb, xT, trend, meanA, stdA, flag);
    myf_k<<<(512 * L2P + 255) / 256, 256, 0, stream>>>(yfw_c, MyfT);
    ceff_k<<<(512 * 64 + 255) / 256, 256, 0, stream>>>(fc4w_c, CeffT);

    // ---- frequency branch (all K multiples of 64 via zero-padding) ----
    G64(stream, trend, L2P, lt1T, L2P, ltb1, nullptr, nullptr, tmp16, NBN, 512, L2P, 2);
    G256(stream, tmp16, 512, lt2T, 512, ltb2, nullptr, fbuf, nullptr, NBN, 512, 512, 0); // t
    G64(stream, xT, L2P, MyfT, L2P, yfb, nullptr, nullptr, yA, NBN, 512, L2P, 5,
        d_in[I_FT], bkey, flag);                                         // -freq gather fused
    G256(stream, yA, 512, ls1T, 512, lsb1, nullptr, nullptr, tmp16, NBN, 512, 512, 2);
    G64(stream, tmp16, 512, ls2T, 512, lsb2, nullptr, nullptr, y49, NBN, 64, 512, 6,
        d_in[I_FT], bkey, flag);             // +freq gather fused; cols 49..63 garbage
    G64(stream, y49, 64, CeffT, 64, fc4b, fbuf, nullptr, xfre16, NBN, 512, 64, 0);
                                             // CeffT cols 49..63 are zero -> garbage killed

    // ---- time embedding ----
    G64(stream, xT, L2P, fc2wT, L2P, fc2b, nullptr, xb32, xb16, NBN, 512, L2P, 0);

    // ---- gating -> bitmask ----
    G256(stream, xb16, 512, gate1w, 512, nullptr, nullptr, nullptr, tmp16, NBN, 512, 512, 1);
    G64(stream, tmp16, 512, tc2T, 256, nullptr, nullptr, xe, nullptr, NBN, 862, 256, 0);
    G64(stream, tmp16 + 256, 512, tn2T, 256, gnoise, xe, xe, nullptr, NBN, 862, 256, 4);
    gating_k<<<NBN, 256, 0, stream>>>(xe, mask64);

    // ---- 2 encoder layers ----
    for (int l = 0; l < 2; l++) {
        G256(stream, xb16, 512, qkvw + (size_t)l * QKVW * 512, 512,
             qkvb + l * QKVW, nullptr, nullptr, qkv16, NBN, QKVW, 512, 0);
        vt_k<<<dim3(NVP / 32, DH / 32, B_ * NH), 256, 0, stream>>>(qkv16, Vt);
        attn_k<<<dim3(14 * 128), 256, 0, stream>>>(qkv16, Vt, mask64, O16);
        G256(stream, O16, 512, woT + (size_t)l * 262144, 512, ebo + l * 512,
             xb32, fbuf, nullptr, NBN, 512, 512, 0);
        ln_k<<<NBN, 256, 0, stream>>>(fbuf, g1v + l * 512, be1v + l * 512, xb32, xb16);
        G256(stream, xb16, 512, c1T + (size_t)l * 524288, 512, c1b + l * 1024,
             nullptr, nullptr, tmp16, NBN, 1024, 512, 3);
        G256(stream, tmp16, 1024, c2T + (size_t)l * 524288, 1024, c2b + l * 512,
             xb32, fbuf, nullptr, NBN, 512, 1024, 0);
        if (l == 0)
            ln_k<<<NBN, 256, 0, stream>>>(fbuf, g2v, be2v, xb32, xb16);
        else
            ln2x_k<<<NBN, 256, 0, stream>>>(fbuf, g2v + 512, be2v + 512, ngv, nbv, xb16);
    }

    // ---- merged output GEMMs ----
    outg_mfma<<<dim3(2, (NBN + 63) / 64, 3), 256, 0, stream>>>(
        xb16, xfre16, fcoT, fc3wT, fc5wT, fcob, fc3b, fc5b,
        rw, rb, meanA, stdA, d_out, flag);
}

// Round 10
// 1629.510 us; speedup vs baseline: 1.5314x; 1.5314x over previous
//
#include <hip/hip_runtime.h>
#include <hip/hip_bf16.h>
#include <math.h>

typedef __hip_bfloat16 bf16;
typedef unsigned long long u64;
using s8v = __attribute__((ext_vector_type(8))) short;
using f4v = __attribute__((ext_vector_type(4))) float;

#define B_   16
#define L_   96
#define NV   862
#define DM   512
#define NH   8
#define DH   64
#define KFL  5000
#define NBN  (B_*NV)   /* 13792 */
#define NVP  896
#define QKVW 1536      /* fused QKV row width */
#define L2P  128       /* padded row stride for xT/trend (K=96 -> 128) */

#define BAR()  __builtin_amdgcn_s_barrier()
#define SCB()  __builtin_amdgcn_sched_barrier(0)
#define VMW0() asm volatile("s_waitcnt vmcnt(0)" ::: "memory")
#define VMW4() asm volatile("s_waitcnt vmcnt(4)" ::: "memory")
#define VMW6() asm volatile("s_waitcnt vmcnt(6)" ::: "memory")
#define VMW8() asm volatile("s_waitcnt vmcnt(8)" ::: "memory")

__device__ __forceinline__ float tof(bf16 x)  { return __bfloat162float(x); }

/* linear-stride-64 LDS swizzled read index (paired with source-side swizzle) */
__device__ __forceinline__ int sxl(int r, int c) {
    return (r << 6) + ((c ^ (r & 7)) << 3);
}
/* P-tile stride-64 swizzle: XOR within 8-row stripe + rotate-2 for rows 8-15. */
__device__ __forceinline__ int px(int r, int k) {
    return (r << 6) + (((((k >> 3) ^ (r & 7)) + ((r & 8) >> 2)) & 7) << 3) + (k & 7);
}
__device__ __forceinline__ int pxc(int r, int c) {
    return (r << 6) + ((((c ^ (r & 7)) + ((r & 8) >> 2)) & 7) << 3);
}

/* async 16B global -> LDS (vmcnt-counted; LDS dest = wave-uniform base + lane*16) */
__device__ __forceinline__ void gl16(const bf16* g, bf16* l)
{
    __builtin_amdgcn_global_load_lds(
        (const __attribute__((address_space(1))) void*)g,
        (__attribute__((address_space(3))) void*)l, 16, 0, 0);
}

/* stage a 64x64 bf16 tile (256 threads): rows clamped to rmax, source column
 * pre-swizzled so linear LDS + sxl() reads line up. 2 VMEM instrs per wave. */
__device__ __forceinline__ void stage64(const bf16* __restrict__ src, int ld,
                                        int r0, int rmax, int k0, bf16* buf, int tid)
{
    #pragma unroll
    for (int i = 0; i < 2; i++) {
        int e = tid + i * 256;
        int r = e >> 3, c = e & 7;
        int gr = r0 + r; gr = gr > rmax ? rmax : gr;
        int gk = k0 + ((c ^ (r & 7)) << 3);
        gl16(src + (size_t)gr * ld + gk, buf + ((size_t)(e >> 6) << 9));
    }
}
/* 128x64 tile variant (256 threads); 4 VMEM instrs per wave */
__device__ __forceinline__ void stage128(const bf16* __restrict__ src, int ld,
                                         int r0, int rmax, int k0, bf16* buf, int tid)
{
    #pragma unroll
    for (int i = 0; i < 4; i++) {
        int e = tid + i * 256;
        int r = e >> 3, c = e & 7;
        int gr = r0 + r; gr = gr > rmax ? rmax : gr;
        int gk = k0 + ((c ^ (r & 7)) << 3);
        gl16(src + (size_t)gr * ld + gk, buf + ((size_t)(e >> 6) << 9));
    }
}
/* 256x64 tile for 1024-thread blocks; 2 VMEM instrs per wave */
__device__ __forceinline__ void stage256k(const bf16* __restrict__ src, int ld,
                                          int r0, int rmax, int k0, bf16* buf, int tid)
{
    #pragma unroll
    for (int i = 0; i < 2; i++) {
        int e = tid + i * 1024;
        int r = e >> 3, c = e & 7;
        int gr = r0 + r; gr = gr > rmax ? rmax : gr;
        int gk = k0 + ((c ^ (r & 7)) << 3);
        gl16(src + (size_t)gr * ld + gk, buf + ((size_t)(e >> 6) << 9));
    }
}

/* bijective XCD-aware block remap (m204): consecutive work chunks per XCD */
__device__ __forceinline__ int xcd_swz(int orig, int nwg)
{
    int q = nwg >> 3, r = nwg & 7;
    int xc = orig & 7, loc = orig >> 3;
    return (xc < r ? xc * (q + 1) : r * (q + 1) + (xc - r) * q) + loc;
}

// ---------------------------------------------------------------------------
__global__ void detect_k(const unsigned short* __restrict__ rw, int* __restrict__ flag)
{
    if (threadIdx.x == 0 && blockIdx.x == 0)
        *flag = (rw[0] == 0 && rw[2] == 0 && rw[4] == 0) ? 1 : 0;
}

// batched flat convert: 30 tensors, one launch
struct CB { const void* src[30]; bf16* dst[30]; int n[30]; int so[30]; };
__global__ __launch_bounds__(256)
void cvtb_k(CB cb, const int* __restrict__ flag)
{
    int t = blockIdx.y;
    int i = blockIdx.x * 256 + threadIdx.x;
    if (i >= cb.n[t]) return;
    int s = cb.so[t] + i;
    if (*flag) cb.dst[t][i] = __float2bfloat16(((const float*)cb.src[t])[s]);
    else       cb.dst[t][i] = ((const bf16*)cb.src[t])[s];
}

// batched transpose-convert: src[srcOff + k*N + n] -> dst[n*Kp + k]; zero-pads
// k in [K, Kp) so pipelined GEMMs can treat K as a multiple of 64
#define NWT 24
struct WD { const void* src; bf16* dst; int K, Kp, N; long srcOff; };
struct WTB { WD d[NWT]; };
__global__ __launch_bounds__(256)
void wtcb_k(WTB wb, const int* __restrict__ flag)
{
    __shared__ bf16 tile[32][33];
    WD dd = wb.d[blockIdx.z];
    int n0 = blockIdx.x * 32, k0 = blockIdx.y * 32;
    if (n0 >= dd.N || k0 >= dd.Kp) return;
    int tx = threadIdx.x & 31, ty = threadIdx.x >> 5;
    int f32 = *flag;
    #pragma unroll
    for (int r = 0; r < 4; r++) {
        int k = k0 + ty + r * 8, n = n0 + tx;
        bf16 v = __float2bfloat16(0.f);
        if (k < dd.K && n < dd.N)
            v = f32 ? __float2bfloat16(((const float*)dd.src)[dd.srcOff + (size_t)k * dd.N + n])
                    : ((const bf16*)dd.src)[dd.srcOff + (size_t)k * dd.N + n];
        tile[ty + r * 8][tx] = v;
    }
    __syncthreads();
    #pragma unroll
    for (int r = 0; r < 4; r++) {
        int n = n0 + ty + r * 8, k = k0 + tx;
        if (n < dd.N && k < dd.Kp) dd.dst[(size_t)n * dd.Kp + k] = tile[tx][ty + r * 8];
    }
}

// ---------------------------------------------------------------------------
// per-(b,h) V transpose from fused QKV
// ---------------------------------------------------------------------------
__global__ __launch_bounds__(256)
void vt_k(const bf16* __restrict__ qkv, bf16* __restrict__ Vt)
{
    __shared__ bf16 t[32][33];
    int bh = blockIdx.z;
    int n0 = blockIdx.x * 32, d0 = blockIdx.y * 32;
    int b = bh >> 3, h = bh & 7;
    int tx = threadIdx.x & 31, ty = threadIdx.x >> 5;
    #pragma unroll
    for (int r = 0; r < 4; r++) {
        int n = n0 + ty + r * 8, d = d0 + tx;
        bf16 v = __float2bfloat16(0.f);
        if (n < NV) v = qkv[(size_t)(b * NV + n) * QKVW + 1024 + h * DH + d];
        t[ty + r * 8][tx] = v;
    }
    __syncthreads();
    #pragma unroll
    for (int r = 0; r < 4; r++) {
        int d = d0 + ty + r * 8, n = n0 + tx;
        Vt[((size_t)bh * DH + d) * NVP + n] = t[tx][ty + r * 8];
    }
}

// ---------------------------------------------------------------------------
// RevIN + trend (xT/trend padded to stride L2P=128, cols 96..127 zero)
// ---------------------------------------------------------------------------
__global__ __launch_bounds__(128)
void revin_k(const void* __restrict__ x_enc, const bf16* __restrict__ rw,
             const bf16* __restrict__ rb, bf16* __restrict__ xT,
             bf16* __restrict__ trend, float* __restrict__ meanA,
             float* __restrict__ stdA, const int* __restrict__ flag)
{
    int row = blockIdx.x;
    int b = row / NV, n = row - b * NV;
    int tid = threadIdx.x;
    int f32 = *flag;
    __shared__ float xr[96];
    __shared__ float part[2][2];
    __shared__ float mv[2];
    float v = 0.f;
    if (tid < 96) {
        size_t idx = ((size_t)b * L_ + tid) * NV + n;
        v = f32 ? ((const float*)x_enc)[idx] : tof(((const bf16*)x_enc)[idx]);
    }
    float s = v, sq = v * v;
    #pragma unroll
    for (int off = 32; off; off >>= 1) {
        s  += __shfl_xor(s,  off, 64);
        sq += __shfl_xor(sq, off, 64);
    }
    int wid = tid >> 6;
    if ((tid & 63) == 0) { part[wid][0] = s; part[wid][1] = sq; }
    __syncthreads();
    if (tid == 0) {
        float S = part[0][0] + part[1][0], Q = part[0][1] + part[1][1];
        float m = S / 96.f;
        float var = fmaxf(Q / 96.f - m * m, 0.f);
        float st = sqrtf(var + 1e-5f);
        mv[0] = m; mv[1] = st;
        meanA[row] = m; stdA[row] = st;
    }
    __syncthreads();
    float m = mv[0], st = mv[1];
    const bf16 z16 = __float2bfloat16(0.f);
    if (tid < 96) {
        float xv = (v - m) / st * tof(rw[n]) + tof(rb[n]);
        xr[tid] = xv;
        xT[(size_t)row * L2P + tid] = __float2bfloat16(xv);
    } else {
        xT[(size_t)row * L2P + tid] = z16;
    }
    __syncthreads();
    if (tid < 96) {
        float acc = 0.f;
        #pragma unroll
        for (int d = -12; d <= 12; d++) {
            int k = tid + d;
            k = k < 0 ? 0 : (k > 95 ? 95 : k);
            acc += xr[k];
        }
        trend[(size_t)row * L2P + tid] = __float2bfloat16(acc * (1.f / 25.f));
    } else {
        trend[(size_t)row * L2P + tid] = z16;
    }
}

// ---------------------------------------------------------------------------
__global__ void myf_k(const bf16* __restrict__ yf_w, bf16* __restrict__ MyfT)
{
    int idx = blockIdx.x * 256 + threadIdx.x;
    if (idx >= 512 * L2P) return;
    int d = idx >> 7, l = idx & 127;
    const float invs = 0.10206207261596575f;
    float acc = 0.f;
    if (l < 96) {
        for (int f = 0; f < 25; f++) {
            float ang = (float)(f * l) / 48.0f;
            acc += cospif(ang) * tof(yf_w[f * 512 + d]);
            acc -= sinpif(ang) * tof(yf_w[(25 + f) * 512 + d]);
        }
        acc *= invs;
    }
    MyfT[(size_t)d * L2P + l] = __float2bfloat16(acc);
}

__global__ void ceff_k(const bf16* __restrict__ fc4_w, bf16* __restrict__ CeffT)
{
    int idx = blockIdx.x * 256 + threadIdx.x;
    if (idx >= 512 * 64) return;
    int d = idx >> 6, f = idx & 63;
    const float invs = 0.10206207261596575f;
    float acc = 0.f;
    if (f < 49) {
        for (int l = 0; l < 96; l++) {
            float coef;
            if (f == 0)       coef = 1.f;
            else if (f == 48) coef = (l & 1) ? -1.f : 1.f;
            else              coef = 2.f * cospif((float)(f * l) / 48.f);
            acc += coef * tof(fc4_w[l * 512 + d]);
        }
        acc *= invs;
    }
    CeffT[(size_t)d * 64 + f] = __float2bfloat16(acc);
}

// ---------------------------------------------------------------------------
// epilogue: act 0 none,1 relu,2 lrelu,3 gelu,4 noisy-gate,
//           5 bias - freq_gather(n), 6 bias + freq_gather(512+n)
// ---------------------------------------------------------------------------
__device__ __forceinline__ float epi(float v, int n, int m, int N, int act,
                                     const bf16* bias, const float* Res,
                                     const void* ft, const int* kf,
                                     const int* dflag)
{
    if (act >= 5) {
        v += tof(bias[n]);
        int b = m / NV, nv = m - b * NV;
        int gi = (act == 5) ? (kf[b] + n) % KFL : (kf[b] + 512 + n) % KFL;
        size_t gidx = (size_t)gi * NV + nv;
        float fv = (*dflag) ? ((const float*)ft)[gidx] : tof(((const bf16*)ft)[gidx]);
        return (act == 5) ? v - fv : v + fv;
    }
    if (act == 4) {
        float z = -(v + 0.01f);
        float sp = fmaxf(z, 0.f) + log1pf(expf(-fabsf(z)));
        return Res[(size_t)m * N + n] + tof(bias[n]) * (-sp);
    }
    if (bias) v += tof(bias[n]);
    if (Res)  v += Res[(size_t)m * N + n];
    if (act == 1)      v = fmaxf(v, 0.f);
    else if (act == 2) v = (v >= 0.f) ? v : 0.01f * v;
    else if (act == 3) v = 0.5f * v * (1.f + erff(v * 0.70710678118654752f));
    return v;
}

// ---------------------------------------------------------------------------
// 256x256 MFMA GEMM, 1024 threads = 16 waves, each computing a 64x64 quadrant
// with acc[4][4] (64 VGPR/thread). This sidesteps the register-allocator
// fight that sank r7/r8/r9 (512-thread variant needs 128 acc VGPRs; allocator
// capped at 100-128 -> spill): per-wave shape is identical to the proven
// gemm128c (92 VGPR, no spill). Occupancy is LDS-pinned (128KB -> 1 blk/CU,
// 4 waves/SIMD) so ~100 VGPRs costs nothing. Counted-vmcnt double buffer.
// ---------------------------------------------------------------------------
__global__ __launch_bounds__(1024, 1)
void gemm256(const bf16* __restrict__ A, int lda,
             const bf16* __restrict__ Wt, int ldb,
             const bf16* __restrict__ bias, const float* Res,
             float* C32, bf16* C16, int M, int N, int K, int act, int gx)
{
    __shared__ __align__(16) bf16 As[2][256 * 64];   // 32 KB x2
    __shared__ __align__(16) bf16 Bs[2][256 * 64];   // 32 KB x2
    int tid = threadIdx.x;
    int w = tid >> 6, lane = tid & 63;
    int lr = lane >> 4, lc = lane & 15;
    int nid = xcd_swz(blockIdx.x, gridDim.x);
    int bx = nid % gx, by = nid / gx;
    int row0 = by * 256, col0 = bx * 256;
    int mq = (w >> 2) * 64;      // 4 row-quadrants
    int nq = (w & 3) * 64;       // 4 col-quadrants
    f4v acc[4][4] = {};
    int nt = K >> 6;
    stage256k(A, lda, row0, M - 1, 0, As[0], tid);
    stage256k(Wt, ldb, col0, N - 1, 0, Bs[0], tid);
    if (nt > 1) {
        stage256k(A, lda, row0, M - 1, 64, As[1], tid);
        stage256k(Wt, ldb, col0, N - 1, 64, Bs[1], tid);
        VMW4();
    } else {
        VMW0();
    }
    BAR(); SCB();
    for (int t = 0; t < nt; t++) {
        int cur = t & 1;
        #pragma unroll
        for (int sub = 0; sub < 2; sub++) {
            int ck = sub * 4 + lr;
            s8v a[4], b[4];
            #pragma unroll
            for (int mt = 0; mt < 4; mt++) a[mt] = *(const s8v*)&As[cur][sxl(mq + mt * 16 + lc, ck)];
            #pragma unroll
            for (int j = 0; j < 4; j++) b[j] = *(const s8v*)&Bs[cur][sxl(nq + j * 16 + lc, ck)];
            #pragma unroll
            for (int mt = 0; mt < 4; mt++)
                #pragma unroll
                for (int j = 0; j < 4; j++)
                    acc[mt][j] = __builtin_amdgcn_mfma_f32_16x16x32_bf16(a[mt], b[j], acc[mt][j], 0, 0, 0);
        }
        if (t + 1 < nt) {
            SCB(); BAR(); SCB();        // all waves done reading buf[cur]
            if (t + 2 < nt) {
                stage256k(A, lda, row0, M - 1, (t + 2) << 6, As[cur], tid);
                stage256k(Wt, ldb, col0, N - 1, (t + 2) << 6, Bs[cur], tid);
                VMW4();                 // t+1's loads complete; t+2's stay in flight
            } else {
                VMW0();
            }
            BAR(); SCB();
        }
    }
    #pragma unroll
    for (int mt = 0; mt < 4; mt++)
    #pragma unroll
    for (int j = 0; j < 4; j++) {
        #pragma unroll
        for (int r = 0; r < 4; r++) {
            int m = row0 + mq + mt * 16 + lr * 4 + r;
            int n = col0 + nq + j * 16 + lc;
            if (m >= M || n >= N) continue;
            float v = epi(acc[mt][j][r], n, m, N, act, bias, Res, nullptr, nullptr, nullptr);
            if (C32) C32[(size_t)m * N + n] = v;
            if (C16) C16[(size_t)m * N + n] = __float2bfloat16(v);
        }
    }
}

// ---------------------------------------------------------------------------
// counted-vmcnt pipelined 128x128 GEMM (r4 form, best-known for these shapes)
// ---------------------------------------------------------------------------
__global__ __launch_bounds__(256)
void gemm128c(const bf16* __restrict__ A, int lda,
              const bf16* __restrict__ Wt, int ldb,
              const bf16* __restrict__ bias, const float* Res,
              float* C32, bf16* C16, int M, int N, int K, int act, int gx)
{
    __shared__ __align__(16) bf16 As[2][128 * 64];
    __shared__ __align__(16) bf16 Bs[2][128 * 64];
    int tid = threadIdx.x;
    int w = tid >> 6, lane = tid & 63;
    int lr = lane >> 4, lc = lane & 15;
    int nid = xcd_swz(blockIdx.x, gridDim.x);
    int bx = nid % gx, by = nid / gx;
    int row0 = by * 128, col0 = bx * 128;
    int mq = (w >> 1) * 64, nq = (w & 1) * 64;
    f4v acc[4][4] = {};
    int nt = K >> 6;
    stage128(A, lda, row0, M - 1, 0, As[0], tid);
    stage128(Wt, ldb, col0, N - 1, 0, Bs[0], tid);
    if (nt > 1) {
        stage128(A, lda, row0, M - 1, 64, As[1], tid);
        stage128(Wt, ldb, col0, N - 1, 64, Bs[1], tid);
        VMW8();
    } else {
        VMW0();
    }
    BAR(); SCB();
    for (int t = 0; t < nt; t++) {
        int cur = t & 1;
        #pragma unroll
        for (int sub = 0; sub < 2; sub++) {
            int ck = sub * 4 + lr;
            s8v a[4], b[4];
            #pragma unroll
            for (int mt = 0; mt < 4; mt++) a[mt] = *(const s8v*)&As[cur][sxl(mq + mt * 16 + lc, ck)];
            #pragma unroll
            for (int j = 0; j < 4; j++) b[j] = *(const s8v*)&Bs[cur][sxl(nq + j * 16 + lc, ck)];
            #pragma unroll
            for (int mt = 0; mt < 4; mt++)
                #pragma unroll
                for (int j = 0; j < 4; j++)
                    acc[mt][j] = __builtin_amdgcn_mfma_f32_16x16x32_bf16(a[mt], b[j], acc[mt][j], 0, 0, 0);
        }
        if (t + 1 < nt) {
            SCB(); BAR(); SCB();
            if (t + 2 < nt) {
                stage128(A, lda, row0, M - 1, (t + 2) << 6, As[cur], tid);
                stage128(Wt, ldb, col0, N - 1, (t + 2) << 6, Bs[cur], tid);
                VMW8();
            } else {
                VMW0();
            }
            BAR(); SCB();
        }
    }
    #pragma unroll
    for (int mt = 0; mt < 4; mt++)
    #pragma unroll
    for (int j = 0; j < 4; j++) {
        #pragma unroll
        for (int r = 0; r < 4; r++) {
            int m = row0 + mq + mt * 16 + lr * 4 + r;
            int n = col0 + nq + j * 16 + lc;
            if (m >= M || n >= N) continue;
            float v = epi(acc[mt][j][r], n, m, N, act, bias, Res, nullptr, nullptr, nullptr);
            if (C32) C32[(size_t)m * N + n] = v;
            if (C16) C16[(size_t)m * N + n] = __float2bfloat16(v);
        }
    }
}

// ---------------------------------------------------------------------------
// counted-vmcnt pipelined 64x128 GEMM (r4 form)
// ---------------------------------------------------------------------------
__global__ __launch_bounds__(256)
void gemm64c(const bf16* __restrict__ A, int lda,
             const bf16* __restrict__ Wt, int ldb,
             const bf16* __restrict__ bias, const float* Res,
             float* C32, bf16* C16, int M, int N, int K, int act,
             const void* ft, const int* kf, const int* dflag, int gx)
{
    __shared__ __align__(16) bf16 As[2][64 * 64];
    __shared__ __align__(16) bf16 Bs[2][128 * 64];
    int tid = threadIdx.x;
    int w = tid >> 6, lane = tid & 63;
    int lr = lane >> 4, lc = lane & 15;
    int nid = xcd_swz(blockIdx.x, gridDim.x);
    int bx = nid % gx, by = nid / gx;
    int row0 = by * 64, col0 = bx * 128;
    int mq = (w >> 1) * 32, nq = (w & 1) * 64;
    f4v acc[2][4] = {};
    int nt = K >> 6;
    stage64(A, lda, row0, M - 1, 0, As[0], tid);
    stage128(Wt, ldb, col0, N - 1, 0, Bs[0], tid);
    if (nt > 1) {
        stage64(A, lda, row0, M - 1, 64, As[1], tid);
        stage128(Wt, ldb, col0, N - 1, 64, Bs[1], tid);
        VMW6();
    } else {
        VMW0();
    }
    BAR(); SCB();
    for (int t = 0; t < nt; t++) {
        int cur = t & 1;
        #pragma unroll
        for (int sub = 0; sub < 2; sub++) {
            int ck = sub * 4 + lr;
            s8v a[2], b[4];
            #pragma unroll
            for (int mt = 0; mt < 2; mt++) a[mt] = *(const s8v*)&As[cur][sxl(mq + mt * 16 + lc, ck)];
            #pragma unroll
            for (int j = 0; j < 4; j++) b[j] = *(const s8v*)&Bs[cur][sxl(nq + j * 16 + lc, ck)];
            #pragma unroll
            for (int mt = 0; mt < 2; mt++)
                #pragma unroll
                for (int j = 0; j < 4; j++)
                    acc[mt][j] = __builtin_amdgcn_mfma_f32_16x16x32_bf16(a[mt], b[j], acc[mt][j], 0, 0, 0);
        }
        if (t + 1 < nt) {
            SCB(); BAR(); SCB();
            if (t + 2 < nt) {
                stage64(A, lda, row0, M - 1, (t + 2) << 6, As[cur], tid);
                stage128(Wt, ldb, col0, N - 1, (t + 2) << 6, Bs[cur], tid);
                VMW6();
            } else {
                VMW0();
            }
            BAR(); SCB();
        }
    }
    #pragma unroll
    for (int mt = 0; mt < 2; mt++)
    #pragma unroll
    for (int j = 0; j < 4; j++) {
        #pragma unroll
        for (int r = 0; r < 4; r++) {
            int m = row0 + mq + mt * 16 + lr * 4 + r;
            int n = col0 + nq + j * 16 + lc;
            if (m >= M || n >= N) continue;
            float v = epi(acc[mt][j][r], n, m, N, act, bias, Res, ft, kf, dflag);
            if (C32) C32[(size_t)m * N + n] = v;
            if (C16) C16[(size_t)m * N + n] = __float2bfloat16(v);
        }
    }
}

// ---------------------------------------------------------------------------
// merged output GEMMs (counted pipeline, r4 form): z in {0:dec, 1:x_time, 2:x_fre}
// ---------------------------------------------------------------------------
__global__ __launch_bounds__(256)
void outg_mfma(const bf16* __restrict__ xb16, const bf16* __restrict__ xfre16,
               const bf16* __restrict__ fcoT, const bf16* __restrict__ fc3T,
               const bf16* __restrict__ fc5T, const bf16* __restrict__ fcob,
               const bf16* __restrict__ fc3b, const bf16* __restrict__ fc5b,
               const bf16* __restrict__ rw, const bf16* __restrict__ rb,
               const float* __restrict__ meanA, const float* __restrict__ stdA,
               void* __restrict__ outv, const int* __restrict__ flag)
{
    __shared__ __align__(16) bf16 As[2][64 * 64];
    __shared__ __align__(16) bf16 Bs[2][64 * 64];
    const int M = NBN, N = 96;
    const size_t OSZ = (size_t)B_ * L_ * NV;
    int z = blockIdx.z;
    const bf16 *A1, *W1, *A2 = nullptr, *W2 = nullptr, *bias;
    int ldb; size_t obase;
    if (z == 0) { A1 = xb16; W1 = fcoT; A2 = xfre16; W2 = fcoT + 512; ldb = 1024; bias = fcob; obase = 0; }
    else if (z == 1) { A1 = xb16; W1 = fc3T; ldb = 512; bias = fc3b; obase = OSZ; }
    else { A1 = xfre16; W1 = fc5T; ldb = 512; bias = fc5b; obase = 2 * OSZ; }
    int tid = threadIdx.x;
    int w = tid >> 6, lane = tid & 63;
    int lr = lane >> 4, lc = lane & 15;
    int row0 = blockIdx.y * 64, col0 = blockIdx.x * 64;
    int mq = (w >> 1) * 32, nq = (w & 1) * 32;
    int f32o = *flag;
    f4v acc[2][2] = {};
    int nt = (z == 0) ? 16 : 8;       // 8 K-steps per 512-wide part
    stage64(A1, 512, row0, M - 1, 0, As[0], tid);
    stage64(W1, ldb, col0, N - 1, 0, Bs[0], tid);
    stage64(A1, 512, row0, M - 1, 64, As[1], tid);
    stage64(W1, ldb, col0, N - 1, 64, Bs[1], tid);
    VMW4();
    BAR(); SCB();
    for (int t = 0; t < nt; t++) {
        int cur = t & 1;
        #pragma unroll
        for (int sub = 0; sub < 2; sub++) {
            int ck = sub * 4 + lr;
            s8v a0 = *(const s8v*)&As[cur][sxl(mq + lc, ck)];
            s8v a1 = *(const s8v*)&As[cur][sxl(mq + 16 + lc, ck)];
            s8v b0 = *(const s8v*)&Bs[cur][sxl(nq + lc, ck)];
            s8v b1 = *(const s8v*)&Bs[cur][sxl(nq + 16 + lc, ck)];
            acc[0][0] = __builtin_amdgcn_mfma_f32_16x16x32_bf16(a0, b0, acc[0][0], 0, 0, 0);
            acc[0][1] = __builtin_amdgcn_mfma_f32_16x16x32_bf16(a0, b1, acc[0][1], 0, 0, 0);
            acc[1][0] = __builtin_amdgcn_mfma_f32_16x16x32_bf16(a1, b0, acc[1][0], 0, 0, 0);
            acc[1][1] = __builtin_amdgcn_mfma_f32_16x16x32_bf16(a1, b1, acc[1][1], 0, 0, 0);
        }
        if (t + 1 < nt) {
            SCB(); BAR(); SCB();
            if (t + 2 < nt) {
                int tn = t + 2;
                const bf16* Ax = (z == 0 && tn >= 8) ? A2 : A1;
                const bf16* Wx = (z == 0 && tn >= 8) ? W2 : W1;
                stage64(Ax, 512, row0, M - 1, (tn & 7) << 6, As[cur], tid);
                stage64(Wx, ldb, col0, N - 1, (tn & 7) << 6, Bs[cur], tid);
                VMW4();
            } else {
                VMW0();
            }
            BAR(); SCB();
        }
    }
    #pragma unroll
    for (int mt = 0; mt < 2; mt++)
    #pragma unroll
    for (int j = 0; j < 2; j++) {
        #pragma unroll
        for (int r = 0; r < 4; r++) {
            int m = row0 + mq + mt * 16 + lr * 4 + r;
            int c = col0 + nq + j * 16 + lc;
            if (m >= M || c >= N) continue;
            int b = m / NV, n = m - b * NV;
            float v = acc[mt][j][r] + tof(bias[c]);
            v = (v - tof(rb[n])) / (tof(rw[n]) + 1e-10f) * stdA[m] + meanA[m];
            size_t oidx = obase + ((size_t)b * L_ + c) * NV + n;
            if (f32o) ((float*)outv)[oidx] = v;
            else      ((bf16*)outv)[oidx] = __float2bfloat16(v);
        }
    }
}

// ---------------------------------------------------------------------------
// Gating -> 64-bit mask words (xe cached in registers: one global read pass)
// ---------------------------------------------------------------------------
__global__ __launch_bounds__(256)
void gating_k(const float* __restrict__ xe, u64* __restrict__ mask64)
{
    int row = blockIdx.x;
    int i = row % NV;
    int tid = threadIdx.x;
    size_t base = (size_t)row * NV;
    float vals[4];
    int cnt = 0;
    float mn = INFINITY, mx = -INFINITY;
    for (int j = tid; j < NV; j += 256) {
        float e = xe[base + j];
        vals[cnt++] = e;
        mn = fminf(mn, e);
        mx = fmaxf(mx, e);
    }
    #pragma unroll
    for (int off = 32; off; off >>= 1) {
        mn = fminf(mn, __shfl_xor(mn, off, 64));
        mx = fmaxf(mx, __shfl_xor(mx, off, 64));
    }
    __shared__ float smn[4], smx[4], fin[2];
    int w = tid >> 6, lane = tid & 63;
    if (lane == 0) { smn[w] = mn; smx[w] = mx; }
    __syncthreads();
    if (tid == 0) {
        float a = fminf(fminf(smn[0], smn[1]), fminf(smn[2], smn[3]));
        float c = fmaxf(fmaxf(smx[0], smx[1]), fmaxf(smx[2], smx[3]));
        fin[0] = a;
        fin[1] = 1.f / (c - a + 1e-6f);
    }
    __syncthreads();
    float a = fin[0], inv = fin[1];
    cnt = 0;
    for (int t = w; t < 14; t += 4) {
        int j = t * 64 + lane;            // == tid + 256*cnt
        bool masked = true;
        if (j < NV) {
            float lg = (vals[cnt++] - a) * inv + ((j == i) ? 1.f : 0.f);
            masked = (lg < 0.5f);
        }
        u64 word = __ballot(masked);
        if (lane == 0) mask64[(size_t)row * 16 + t] = word;
    }
}

// ---------------------------------------------------------------------------
__global__ __launch_bounds__(256)
void ln_k(const float* __restrict__ X, const bf16* __restrict__ g,
          const bf16* __restrict__ bta, float* __restrict__ Y32,
          bf16* __restrict__ Y16)
{
    int row = blockIdx.x;
    int tid = threadIdx.x;
    size_t base = (size_t)row * DM;
    float v0 = X[base + tid], v1 = X[base + tid + 256];
    float s = v0 + v1, sq = v0 * v0 + v1 * v1;
    #pragma unroll
    for (int off = 32; off; off >>= 1) {
        s  += __shfl_xor(s,  off, 64);
        sq += __shfl_xor(sq, off, 64);
    }
    __shared__ float ps[4], pq[4], mv[2];
    int wid = tid >> 6;
    if ((tid & 63) == 0) { ps[wid] = s; pq[wid] = sq; }
    __syncthreads();
    if (tid == 0) {
        float S = ps[0] + ps[1] + ps[2] + ps[3];
        float Q = pq[0] + pq[1] + pq[2] + pq[3];
        float m = S / 512.f;
        float var = fmaxf(Q / 512.f - m * m, 0.f);
        mv[0] = m;
        mv[1] = rsqrtf(var + 1e-5f);
    }
    __syncthreads();
    float m = mv[0], r = mv[1];
    float o0 = (v0 - m) * r * tof(g[tid])       + tof(bta[tid]);
    float o1 = (v1 - m) * r * tof(g[tid + 256]) + tof(bta[tid + 256]);
    if (Y32) { Y32[base + tid] = o0; Y32[base + tid + 256] = o1; }
    if (Y16) { Y16[base + tid] = __float2bfloat16(o0);
               Y16[base + tid + 256] = __float2bfloat16(o1); }
}

// ---------------------------------------------------------------------------
// Double LayerNorm (layer-2 second LN fused with final norm): z=LN(LN(x)g1+b1)g2+b2
// ---------------------------------------------------------------------------
__global__ __launch_bounds__(256)
void ln2x_k(const float* __restrict__ X, const bf16* __restrict__ g1,
            const bf16* __restrict__ b1, const bf16* __restrict__ g2,
            const bf16* __restrict__ b2, bf16* __restrict__ Y16)
{
    int row = blockIdx.x;
    int tid = threadIdx.x;
    size_t base = (size_t)row * DM;
    float v0 = X[base + tid], v1 = X[base + tid + 256];
    __shared__ float ps[4], pq[4], mv[2];
    int wid = tid >> 6;
    // pass 1
    {
        float s = v0 + v1, sq = v0 * v0 + v1 * v1;
        #pragma unroll
        for (int off = 32; off; off >>= 1) {
            s  += __shfl_xor(s,  off, 64);
            sq += __shfl_xor(sq, off, 64);
        }
        if ((tid & 63) == 0) { ps[wid] = s; pq[wid] = sq; }
        __syncthreads();
        if (tid == 0) {
            float S = ps[0] + ps[1] + ps[2] + ps[3];
            float Q = pq[0] + pq[1] + pq[2] + pq[3];
            float m = S / 512.f;
            float var = fmaxf(Q / 512.f - m * m, 0.f);
            mv[0] = m; mv[1] = rsqrtf(var + 1e-5f);
        }
        __syncthreads();
    }
    float m1 = mv[0], r1 = mv[1];
    float y0 = (v0 - m1) * r1 * tof(g1[tid])       + tof(b1[tid]);
    float y1 = (v1 - m1) * r1 * tof(g1[tid + 256]) + tof(b1[tid + 256]);
    __syncthreads();
    // pass 2
    {
        float s = y0 + y1, sq = y0 * y0 + y1 * y1;
        #pragma unroll
        for (int off = 32; off; off >>= 1) {
            s  += __shfl_xor(s,  off, 64);
            sq += __shfl_xor(sq, off, 64);
        }
        if ((tid & 63) == 0) { ps[wid] = s; pq[wid] = sq; }
        __syncthreads();
        if (tid == 0) {
            float S = ps[0] + ps[1] + ps[2] + ps[3];
            float Q = pq[0] + pq[1] + pq[2] + pq[3];
            float m = S / 512.f;
            float var = fmaxf(Q / 512.f - m * m, 0.f);
            mv[0] = m; mv[1] = rsqrtf(var + 1e-5f);
        }
        __syncthreads();
    }
    float m2 = mv[0], r2 = mv[1];
    Y16[base + tid]       = __float2bfloat16((y0 - m2) * r2 * tof(g2[tid])       + tof(b2[tid]));
    Y16[base + tid + 256] = __float2bfloat16((y1 - m2) * r2 * tof(g2[tid + 256]) + tof(b2[tid + 256]));
}

// ---------------------------------------------------------------------------
// Flash MFMA attention v7 (r4 form): LDS-staged K/V via global_load_lds +
// counted-vmcnt double buffer, conflict-free stride-64 layout, px/pxc P-tile.
// ---------------------------------------------------------------------------
__global__ __launch_bounds__(256)
void attn_k(const bf16* __restrict__ qkv, const bf16* __restrict__ Vt,
            const u64* __restrict__ mask64, bf16* __restrict__ O)
{
    __shared__ __align__(16) bf16 Ks[2][64 * 64];
    __shared__ __align__(16) bf16 Vs[2][64 * 64];
    __shared__ bf16 Pt[4][16 * 64];
    int bid = blockIdx.x;
    int bh = bid & 127;                 // B*NH = 128, fastest -> same XCD per (b,h)
    int q0 = (bid >> 7) * 64;
    int b = bh >> 3, h = bh & 7;
    int tid = threadIdx.x;
    int w = tid >> 6, lane = tid & 63;
    int lr = lane >> 4, lc = lane & 15;
    size_t hb = (size_t)h * DH;
    int qw = q0 + w * 16;
    const float C = 0.18033688011112042f;   // 0.125 * log2(e)

    s8v qf[2];
    #pragma unroll
    for (int sub = 0; sub < 2; sub++) {
        int gq = qw + lc;
        uint4 v = make_uint4(0, 0, 0, 0);
        if (gq < NV)
            v = *(const uint4*)(qkv + ((size_t)(b * NV + gq)) * QKVW + hb + sub * 32 + lr * 8);
        qf[sub] = *(s8v*)&v;
    }

    const bf16* kbase = qkv + (size_t)b * NV * QKVW + 512 + hb;  // row = key, 64 cols
    const bf16* vbase = Vt + (size_t)bh * DH * NVP;              // row = d, NVP cols

    float lsum[4] = {0.f, 0.f, 0.f, 0.f};
    f4v oacc[4] = {};
    const int NT = 14;

    // prologue: stage tiles 0 and 1 (4 VMEM/wave each)
    stage64(kbase, QKVW, 0, NV - 1, 0, Ks[0], tid);
    stage64(vbase, NVP, 0, DH - 1, 0, Vs[0], tid);
    stage64(kbase, QKVW, 64, NV - 1, 0, Ks[1], tid);
    stage64(vbase, NVP, 0, DH - 1, 64, Vs[1], tid);
    VMW4();                             // tile 0 complete; tile 1 in flight
    BAR(); SCB();

    for (int t = 0; t < NT; t++) {
        int cur = t & 1;
        // ---- QK^T from LDS (conflict-free sxl layout) ----
        f4v s[4];
        __builtin_amdgcn_s_setprio(1);
        #pragma unroll
        for (int nt = 0; nt < 4; nt++) {
            f4v sacc = {0.f, 0.f, 0.f, 0.f};
            #pragma unroll
            for (int sub = 0; sub < 2; sub++) {
                s8v bb = *(const s8v*)&Ks[cur][sxl(nt * 16 + lc, sub * 4 + lr)];
                sacc = __builtin_amdgcn_mfma_f32_16x16x32_bf16(qf[sub], bb, sacc, 0, 0, 0);
            }
            s[nt] = sacc;
        }
        __builtin_amdgcn_s_setprio(0);
        // ---- P = exp2(s*C), masked via per-row global mask word ----
        #pragma unroll
        for (int r = 0; r < 4; r++) {
            int gq = qw + lr * 4 + r;
            u64 wd = (gq < NV) ? mask64[(size_t)(b * NV + gq) * 16 + t] : ~0ull;
            #pragma unroll
            for (int nt = 0; nt < 4; nt++) {
                float p = ((wd >> (nt * 16 + lc)) & 1) ? 0.f : exp2f(s[nt][r] * C);
                Pt[w][px(lr * 4 + r, nt * 16 + lc)] = __float2bfloat16(p);
                lsum[r] += p;
            }
        }
        // ---- P @ V from LDS (Pt wave-private, RAW via lgkmcnt) ----
        #pragma unroll
        for (int sub = 0; sub < 2; sub++) {
            s8v pa = *(const s8v*)&Pt[w][pxc(lc, sub * 4 + lr)];
            __builtin_amdgcn_s_setprio(1);
            #pragma unroll
            for (int dt = 0; dt < 4; dt++) {
                s8v vv = *(const s8v*)&Vs[cur][sxl(dt * 16 + lc, sub * 4 + lr)];
                oacc[dt] = __builtin_amdgcn_mfma_f32_16x16x32_bf16(pa, vv, oacc[dt], 0, 0, 0);
            }
            __builtin_amdgcn_s_setprio(0);
        }
        if (t + 1 < NT) {
            SCB(); BAR(); SCB();        // all waves done reading buf[cur]
            if (t + 2 < NT) {
                int j2 = (t + 2) * 64;
                stage64(kbase, QKVW, j2, NV - 1, 0, Ks[cur], tid);
                stage64(vbase, NVP, 0, DH - 1, j2, Vs[cur], tid);
                VMW4();                 // t+1 complete; t+2 in flight
            } else {
                VMW0();
            }
            BAR(); SCB();
        }
    }
    // one deferred row-sum reduction over the 16 lanes sharing each row
    #pragma unroll
    for (int r = 0; r < 4; r++) {
        #pragma unroll
        for (int o2 = 1; o2 < 16; o2 <<= 1) lsum[r] += __shfl_xor(lsum[r], o2, 64);
    }
    #pragma unroll
    for (int r = 0; r < 4; r++) {
        int gq = qw + lr * 4 + r;
        if (gq >= NV) continue;
        float linv = 1.f / fmaxf(lsum[r], 1e-30f);
        #pragma unroll
        for (int dt = 0; dt < 4; dt++)
            O[((size_t)(b * NV + gq)) * DM + hb + dt * 16 + lc] =
                __float2bfloat16(oacc[dt][r] * linv);
    }
}

// ---------------------------------------------------------------------------
static void G256(hipStream_t s, const bf16* A, int lda, const bf16* Wt, int ldb,
                 const bf16* bias, const float* Res, float* C32, bf16* C16,
                 int M, int N, int K, int act)
{
    int gx = (N + 255) / 256, gy = (M + 255) / 256;
    gemm256<<<dim3(gx * gy), 1024, 0, s>>>(A, lda, Wt, ldb, bias, Res, C32, C16,
                                           M, N, K, act, gx);
}
static void G1(hipStream_t s, const bf16* A, int lda, const bf16* Wt, int ldb,
               const bf16* bias, const float* Res, float* C32, bf16* C16,
               int M, int N, int K, int act)
{
    int gx = (N + 127) / 128, gy = (M + 127) / 128;
    gemm128c<<<dim3(gx * gy), 256, 0, s>>>(A, lda, Wt, ldb, bias, Res, C32, C16, M, N, K, act, gx);
}
static void G64(hipStream_t s, const bf16* A, int lda, const bf16* Wt, int ldb,
                const bf16* bias, const float* Res, float* C32, bf16* C16,
                int M, int N, int K, int act,
                const void* ft = nullptr, const int* kf = nullptr, const int* df = nullptr)
{
    int gx = (N + 127) / 128, gy = (M + 63) / 64;
    gemm64c<<<dim3(gx * gy), 256, 0, s>>>(A, lda, Wt, ldb, bias, Res, C32, C16, M, N, K, act, ft, kf, df, gx);
}

enum { I_XENC = 0, I_GNOISE, I_RW, I_RB, I_FC2W, I_FC2B, I_FC3W, I_FC3B,
       I_FC4W, I_FC4B, I_FC5W, I_FC5B, I_TCW1, I_TCW2, I_TNW1, I_TNW2,
       I_LTW1, I_LTB1, I_LTW2, I_LTB2, I_YFW, I_YFB, I_LSW1, I_LSB1,
       I_LSW2, I_LSB2, I_FCOW, I_FCOB, I_FT, I_EWQ, I_EBQ, I_EWK, I_EBK,
       I_EWV, I_EBV, I_EWO, I_EBO, I_C1W, I_C1B, I_C2W, I_C2B,
       I_G1, I_BE1, I_G2, I_BE2, I_NG, I_NB };

extern "C" void kernel_launch(void* const* d_in, const int* in_sizes, int n_in,
                              void* d_out, int out_size, void* d_ws, size_t ws_size,
                              hipStream_t stream)
{
    const int* bkey = (const int*)d_in[47];
    (void)ws_size; (void)in_sizes; (void)n_in; (void)out_size;

    // ---- arena (~190 MB) ----
    float* ws = (float*)d_ws;
    size_t off = 0;
    auto alloc = [&](size_t nf) { nf = (nf + 3) & ~(size_t)3; float* p = ws + off; off += nf; return p; };
    auto balloc = [&](size_t nb) { return (bf16*)alloc((nb + 1) / 2); };
    int*  flag  = (int*)alloc(16);
    bf16* gnoise = balloc(862); bf16* rw = balloc(862); bf16* rb = balloc(862);
    bf16* fc2b = balloc(512);  bf16* fc3b = balloc(96);
    bf16* fc4w_c = balloc(49152); bf16* fc4b = balloc(512); bf16* fc5b = balloc(96);
    bf16* ltb1 = balloc(512);  bf16* ltb2 = balloc(512);
    bf16* yfw_c = balloc(25600); bf16* yfb = balloc(512);
    bf16* lsb1 = balloc(512);  bf16* lsb2 = balloc(512);
    bf16* fcob = balloc(96);
    bf16* qkvb = balloc(2 * QKVW);
    bf16* ebo = balloc(1024);  bf16* c1b = balloc(2048); bf16* c2b = balloc(1024);
    bf16* g1v = balloc(1024);  bf16* be1v = balloc(1024);
    bf16* g2v = balloc(1024);  bf16* be2v = balloc(1024);
    bf16* ngv = balloc(512);   bf16* nbv = balloc(512);
    bf16* fc2wT = balloc(512 * L2P);  bf16* fc3wT = balloc(49152); bf16* fc5wT = balloc(49152);
    bf16* lt1T = balloc(512 * L2P);   bf16* lt2T = balloc(262144);
    bf16* ls1T = balloc(262144);  bf16* ls2T = balloc(262144);
    bf16* fcoT = balloc(98304);
    bf16* tc2T = balloc(220672);  bf16* tn2T = balloc(220672);
    bf16* gate1w = balloc(262144);
    bf16* qkvw = balloc(2 * QKVW * 512);
    bf16* woT = balloc(524288);
    bf16* c1T = balloc(1048576);  bf16* c2T = balloc(1048576);
    bf16* xT    = balloc((size_t)NBN * L2P);
    bf16* trend = balloc((size_t)NBN * L2P);
    float* meanA = alloc(13824);
    float* stdA  = alloc(13824);
    bf16* MyfT  = balloc(512 * L2P);
    bf16* CeffT = balloc(512 * 64);
    bf16* y49   = balloc((size_t)NBN * 64);
    float* xb32 = alloc((size_t)NBN * 512);
    bf16* xb16  = balloc((size_t)NBN * 512);
    bf16* xfre16 = balloc((size_t)NBN * 512);
    bf16* tmp16 = balloc((size_t)NBN * 1024);   // FF hidden / gate1 / Vt / freq scratch
    float* fbuf = alloc((size_t)NBN * 512);
    float* gbuf = alloc((size_t)NBN * 1024);    // xe fp32 / yA / qkv16+O16
    u64* mask64 = (u64*)alloc((size_t)NBN * 32);

    float* xe = gbuf;
    bf16* yA  = (bf16*)gbuf;
    bf16* qkv16 = (bf16*)gbuf;                  // [NBN][1536]
    bf16* O16 = qkv16 + (size_t)NBN * QKVW;     // [NBN][512]
    bf16* Vt  = tmp16;                          // [128][64][896]

    detect_k<<<1, 64, 0, stream>>>((const unsigned short*)d_in[I_RW], flag);

    // ---- batched flat conversions ----
    {
        CB cb;
        int k = 0;
        auto add = [&](int idx, bf16* dst, int n, int so) {
            cb.src[k] = d_in[idx]; cb.dst[k] = dst; cb.n[k] = n; cb.so[k] = so; k++;
        };
        add(I_GNOISE, gnoise, 862, 0); add(I_RW, rw, 862, 0); add(I_RB, rb, 862, 0);
        add(I_FC2B, fc2b, 512, 0); add(I_FC3B, fc3b, 96, 0);
        add(I_FC4W, fc4w_c, 49152, 0); add(I_FC4B, fc4b, 512, 0); add(I_FC5B, fc5b, 96, 0);
        add(I_LTB1, ltb1, 512, 0); add(I_LTB2, ltb2, 512, 0);
        add(I_YFW, yfw_c, 25600, 0); add(I_YFB, yfb, 512, 0);
        add(I_LSB1, lsb1, 512, 0); add(I_LSB2, lsb2, 512, 0);
        add(I_FCOB, fcob, 96, 0);
        add(I_EBQ, qkvb + 0, 512, 0);          add(I_EBQ, qkvb + QKVW, 512, 512);
        add(I_EBK, qkvb + 512, 512, 0);        add(I_EBK, qkvb + QKVW + 512, 512, 512);
        add(I_EBV, qkvb + 1024, 512, 0);       add(I_EBV, qkvb + QKVW + 1024, 512, 512);
        add(I_EBO, ebo, 1024, 0); add(I_C1B, c1b, 2048, 0); add(I_C2B, c2b, 1024, 0);
        add(I_G1, g1v, 1024, 0); add(I_BE1, be1v, 1024, 0);
        add(I_G2, g2v, 1024, 0); add(I_BE2, be2v, 1024, 0);
        add(I_NG, ngv, 512, 0); add(I_NB, nbv, 512, 0);
        cvtb_k<<<dim3(192, 30), 256, 0, stream>>>(cb, flag);
    }

    // ---- batched weight transposes (24 entries, one launch; Kp-padded) ----
    {
        WTB wb;
        int k = 0;
        auto add = [&](int idx, bf16* dst, int K, int Kp, int N, long soff) {
            wb.d[k].src = d_in[idx]; wb.d[k].dst = dst;
            wb.d[k].K = K; wb.d[k].Kp = Kp; wb.d[k].N = N; wb.d[k].srcOff = soff; k++;
        };
        add(I_FC2W, fc2wT, 96, L2P, 512, 0);
        add(I_FC3W, fc3wT, 512, 512, 96, 0);
        add(I_FC5W, fc5wT, 512, 512, 96, 0);
        add(I_LTW1, lt1T, 96, L2P, 512, 0);
        add(I_LTW2, lt2T, 512, 512, 512, 0);
        add(I_LSW1, ls1T, 512, 512, 512, 0);
        add(I_LSW2, ls2T, 512, 512, 512, 0);
        add(I_FCOW, fcoT, 1024, 1024, 96, 0);
        add(I_TCW2, tc2T, 256, 256, 862, 0);
        add(I_TNW2, tn2T, 256, 256, 862, 0);
        add(I_TCW1, gate1w, 512, 512, 256, 0);
        add(I_TNW1, gate1w + 256 * 512, 512, 512, 256, 0);
        for (int l = 0; l < 2; l++) {
            add(I_EWO, woT + (size_t)l * 262144, 512, 512, 512, (long)l * 262144);
            add(I_C1W, c1T + (size_t)l * 524288, 512, 512, 1024, (long)l * 524288);
            add(I_C2W, c2T + (size_t)l * 524288, 1024, 1024, 512, (long)l * 524288);
            add(I_EWQ, qkvw + (size_t)l * 786432 + 0,      512, 512, 512, (long)l * 262144);
            add(I_EWK, qkvw + (size_t)l * 786432 + 262144, 512, 512, 512, (long)l * 262144);
            add(I_EWV, qkvw + (size_t)l * 786432 + 524288, 512, 512, 512, (long)l * 262144);
        }
        wtcb_k<<<dim3(32, 32, NWT), 256, 0, stream>>>(wb, flag);
    }

    // ---- RevIN + trend; DFT/IDFT folds ----
    revin_k<<<NBN, 128, 0, stream>>>(d_in[I_XENC], rw, rb, xT, trend, meanA, stdA, flag);
    myf_k<<<(512 * L2P + 255) / 256, 256, 0, stream>>>(yfw_c, MyfT);
    ceff_k<<<(512 * 64 + 255) / 256, 256, 0, stream>>>(fc4w_c, CeffT);

    // ---- frequency branch (all K multiples of 64 via zero-padding) ----
    G64(stream, trend, L2P, lt1T, L2P, ltb1, nullptr, nullptr, tmp16, NBN, 512, L2P, 2);
    G256(stream, tmp16, 512, lt2T, 512, ltb2, nullptr, fbuf, nullptr, NBN, 512, 512, 0); // t
    G64(stream, xT, L2P, MyfT, L2P, yfb, nullptr, nullptr, yA, NBN, 512, L2P, 5,
        d_in[I_FT], bkey, flag);                                         // -freq gather fused
    G256(stream, yA, 512, ls1T, 512, lsb1, nullptr, nullptr, tmp16, NBN, 512, 512, 2);
    G64(stream, tmp16, 512, ls2T, 512, lsb2, nullptr, nullptr, y49, NBN, 64, 512, 6,
        d_in[I_FT], bkey, flag);             // +freq gather fused; cols 49..63 garbage
    G64(stream, y49, 64, CeffT, 64, fc4b, fbuf, nullptr, xfre16, NBN, 512, 64, 0);
                                             // CeffT cols 49..63 are zero -> garbage killed

    // ---- time embedding ----
    G64(stream, xT, L2P, fc2wT, L2P, fc2b, nullptr, xb32, xb16, NBN, 512, L2P, 0);

    // ---- gating -> bitmask ----
    G256(stream, xb16, 512, gate1w, 512, nullptr, nullptr, nullptr, tmp16, NBN, 512, 512, 1);
    G64(stream, tmp16, 512, tc2T, 256, nullptr, nullptr, xe, nullptr, NBN, 862, 256, 0);
    G64(stream, tmp16 + 256, 512, tn2T, 256, gnoise, xe, xe, nullptr, NBN, 862, 256, 4);
    gating_k<<<NBN, 256, 0, stream>>>(xe, mask64);

    // ---- 2 encoder layers ----
    for (int l = 0; l < 2; l++) {
        G256(stream, xb16, 512, qkvw + (size_t)l * QKVW * 512, 512,
             qkvb + l * QKVW, nullptr, nullptr, qkv16, NBN, QKVW, 512, 0);
        vt_k<<<dim3(NVP / 32, DH / 32, B_ * NH), 256, 0, stream>>>(qkv16, Vt);
        attn_k<<<dim3(14 * 128), 256, 0, stream>>>(qkv16, Vt, mask64, O16);
        G256(stream, O16, 512, woT + (size_t)l * 262144, 512, ebo + l * 512,
             xb32, fbuf, nullptr, NBN, 512, 512, 0);
        ln_k<<<NBN, 256, 0, stream>>>(fbuf, g1v + l * 512, be1v + l * 512, xb32, xb16);
        G256(stream, xb16, 512, c1T + (size_t)l * 524288, 512, c1b + l * 1024,
             nullptr, nullptr, tmp16, NBN, 1024, 512, 3);
        G256(stream, tmp16, 1024, c2T + (size_t)l * 524288, 1024, c2b + l * 512,
             xb32, fbuf, nullptr, NBN, 512, 1024, 0);
        if (l == 0)
            ln_k<<<NBN, 256, 0, stream>>>(fbuf, g2v, be2v, xb32, xb16);
        else
            ln2x_k<<<NBN, 256, 0, stream>>>(fbuf, g2v + 512, be2v + 512, ngv, nbv, xb16);
    }

    // ---- merged output GEMMs ----
    outg_mfma<<<dim3(2, (NBN + 63) / 64, 3), 256, 0, stream>>>(
        xb16, xfre16, fcoT, fc3wT, fc5wT, fcob, fc3b, fc5b,
        rw, rb, meanA, stdA, d_out, flag);
}

// Round 11
// 1460.885 us; speedup vs baseline: 1.7082x; 1.1154x over previous
//
#include <hip/hip_runtime.h>
#include <hip/hip_bf16.h>
#include <math.h>

typedef __hip_bfloat16 bf16;
typedef unsigned long long u64;
using s8v = __attribute__((ext_vector_type(8))) short;
using f4v = __attribute__((ext_vector_type(4))) float;

#define B_   16
#define L_   96
#define NV   862
#define DM   512
#define NH   8
#define DH   64
#define KFL  5000
#define NBN  (B_*NV)   /* 13792 */
#define NVP  896
#define QKVW 1536      /* fused QKV row width */
#define L2P  128       /* padded row stride for xT/trend (K=96 -> 128) */

#define BAR()  __builtin_amdgcn_s_barrier()
#define SCB()  __builtin_amdgcn_sched_barrier(0)
#define VMW0() asm volatile("s_waitcnt vmcnt(0)" ::: "memory")
#define VMW4() asm volatile("s_waitcnt vmcnt(4)" ::: "memory")
#define VMW6() asm volatile("s_waitcnt vmcnt(6)" ::: "memory")
#define VMW8() asm volatile("s_waitcnt vmcnt(8)" ::: "memory")

__device__ __forceinline__ float tof(bf16 x)  { return __bfloat162float(x); }

/* linear-stride-64 LDS swizzled read index (paired with source-side swizzle) */
__device__ __forceinline__ int sxl(int r, int c) {
    return (r << 6) + ((c ^ (r & 7)) << 3);
}
/* P-tile stride-64 swizzle: XOR within 8-row stripe + rotate-2 for rows 8-15. */
__device__ __forceinline__ int px(int r, int k) {
    return (r << 6) + (((((k >> 3) ^ (r & 7)) + ((r & 8) >> 2)) & 7) << 3) + (k & 7);
}
__device__ __forceinline__ int pxc(int r, int c) {
    return (r << 6) + ((((c ^ (r & 7)) + ((r & 8) >> 2)) & 7) << 3);
}

/* async 16B global -> LDS (vmcnt-counted; LDS dest = wave-uniform base + lane*16) */
__device__ __forceinline__ void gl16(const bf16* g, bf16* l)
{
    __builtin_amdgcn_global_load_lds(
        (const __attribute__((address_space(1))) void*)g,
        (__attribute__((address_space(3))) void*)l, 16, 0, 0);
}

/* stage a 64x64 bf16 tile (256 threads): rows clamped to rmax, source column
 * pre-swizzled so linear LDS + sxl() reads line up. 2 VMEM instrs per wave. */
__device__ __forceinline__ void stage64(const bf16* __restrict__ src, int ld,
                                        int r0, int rmax, int k0, bf16* buf, int tid)
{
    #pragma unroll
    for (int i = 0; i < 2; i++) {
        int e = tid + i * 256;
        int r = e >> 3, c = e & 7;
        int gr = r0 + r; gr = gr > rmax ? rmax : gr;
        int gk = k0 + ((c ^ (r & 7)) << 3);
        gl16(src + (size_t)gr * ld + gk, buf + ((size_t)(e >> 6) << 9));
    }
}
/* 128x64 tile variant (256 threads); 4 VMEM instrs per wave */
__device__ __forceinline__ void stage128(const bf16* __restrict__ src, int ld,
                                         int r0, int rmax, int k0, bf16* buf, int tid)
{
    #pragma unroll
    for (int i = 0; i < 4; i++) {
        int e = tid + i * 256;
        int r = e >> 3, c = e & 7;
        int gr = r0 + r; gr = gr > rmax ? rmax : gr;
        int gk = k0 + ((c ^ (r & 7)) << 3);
        gl16(src + (size_t)gr * ld + gk, buf + ((size_t)(e >> 6) << 9));
    }
}
/* 256x64 tile for 1024-thread blocks; 2 VMEM instrs per wave */
__device__ __forceinline__ void stage256k(const bf16* __restrict__ src, int ld,
                                          int r0, int rmax, int k0, bf16* buf, int tid)
{
    #pragma unroll
    for (int i = 0; i < 2; i++) {
        int e = tid + i * 1024;
        int r = e >> 3, c = e & 7;
        int gr = r0 + r; gr = gr > rmax ? rmax : gr;
        int gk = k0 + ((c ^ (r & 7)) << 3);
        gl16(src + (size_t)gr * ld + gk, buf + ((size_t)(e >> 6) << 9));
    }
}

/* bijective XCD-aware block remap (m204): consecutive work chunks per XCD */
__device__ __forceinline__ int xcd_swz(int orig, int nwg)
{
    int q = nwg >> 3, r = nwg & 7;
    int xc = orig & 7, loc = orig >> 3;
    return (xc < r ? xc * (q + 1) : r * (q + 1) + (xc - r) * q) + loc;
}

// ---------------------------------------------------------------------------
__global__ void detect_k(const unsigned short* __restrict__ rw, int* __restrict__ flag)
{
    if (threadIdx.x == 0 && blockIdx.x == 0)
        *flag = (rw[0] == 0 && rw[2] == 0 && rw[4] == 0) ? 1 : 0;
}

// batched flat convert: 30 tensors, one launch
struct CB { const void* src[30]; bf16* dst[30]; int n[30]; int so[30]; };
__global__ __launch_bounds__(256)
void cvtb_k(CB cb, const int* __restrict__ flag)
{
    int t = blockIdx.y;
    int i = blockIdx.x * 256 + threadIdx.x;
    if (i >= cb.n[t]) return;
    int s = cb.so[t] + i;
    if (*flag) cb.dst[t][i] = __float2bfloat16(((const float*)cb.src[t])[s]);
    else       cb.dst[t][i] = ((const bf16*)cb.src[t])[s];
}

// batched transpose-convert: src[srcOff + k*N + n] -> dst[n*Kp + k]; zero-pads
// k in [K, Kp) so pipelined GEMMs can treat K as a multiple of 64
#define NWT 24
struct WD { const void* src; bf16* dst; int K, Kp, N; long srcOff; };
struct WTB { WD d[NWT]; };
__global__ __launch_bounds__(256)
void wtcb_k(WTB wb, const int* __restrict__ flag)
{
    __shared__ bf16 tile[32][33];
    WD dd = wb.d[blockIdx.z];
    int n0 = blockIdx.x * 32, k0 = blockIdx.y * 32;
    if (n0 >= dd.N || k0 >= dd.Kp) return;
    int tx = threadIdx.x & 31, ty = threadIdx.x >> 5;
    int f32 = *flag;
    #pragma unroll
    for (int r = 0; r < 4; r++) {
        int k = k0 + ty + r * 8, n = n0 + tx;
        bf16 v = __float2bfloat16(0.f);
        if (k < dd.K && n < dd.N)
            v = f32 ? __float2bfloat16(((const float*)dd.src)[dd.srcOff + (size_t)k * dd.N + n])
                    : ((const bf16*)dd.src)[dd.srcOff + (size_t)k * dd.N + n];
        tile[ty + r * 8][tx] = v;
    }
    __syncthreads();
    #pragma unroll
    for (int r = 0; r < 4; r++) {
        int n = n0 + ty + r * 8, k = k0 + tx;
        if (n < dd.N && k < dd.Kp) dd.dst[(size_t)n * dd.Kp + k] = tile[tx][ty + r * 8];
    }
}

// ---------------------------------------------------------------------------
// per-(b,h) V transpose from fused QKV
// ---------------------------------------------------------------------------
__global__ __launch_bounds__(256)
void vt_k(const bf16* __restrict__ qkv, bf16* __restrict__ Vt)
{
    __shared__ bf16 t[32][33];
    int bh = blockIdx.z;
    int n0 = blockIdx.x * 32, d0 = blockIdx.y * 32;
    int b = bh >> 3, h = bh & 7;
    int tx = threadIdx.x & 31, ty = threadIdx.x >> 5;
    #pragma unroll
    for (int r = 0; r < 4; r++) {
        int n = n0 + ty + r * 8, d = d0 + tx;
        bf16 v = __float2bfloat16(0.f);
        if (n < NV) v = qkv[(size_t)(b * NV + n) * QKVW + 1024 + h * DH + d];
        t[ty + r * 8][tx] = v;
    }
    __syncthreads();
    #pragma unroll
    for (int r = 0; r < 4; r++) {
        int d = d0 + ty + r * 8, n = n0 + tx;
        Vt[((size_t)bh * DH + d) * NVP + n] = t[tx][ty + r * 8];
    }
}

// ---------------------------------------------------------------------------
// RevIN + trend (xT/trend padded to stride L2P=128, cols 96..127 zero)
// ---------------------------------------------------------------------------
__global__ __launch_bounds__(128)
void revin_k(const void* __restrict__ x_enc, const bf16* __restrict__ rw,
             const bf16* __restrict__ rb, bf16* __restrict__ xT,
             bf16* __restrict__ trend, float* __restrict__ meanA,
             float* __restrict__ stdA, const int* __restrict__ flag)
{
    int row = blockIdx.x;
    int b = row / NV, n = row - b * NV;
    int tid = threadIdx.x;
    int f32 = *flag;
    __shared__ float xr[96];
    __shared__ float part[2][2];
    __shared__ float mv[2];
    float v = 0.f;
    if (tid < 96) {
        size_t idx = ((size_t)b * L_ + tid) * NV + n;
        v = f32 ? ((const float*)x_enc)[idx] : tof(((const bf16*)x_enc)[idx]);
    }
    float s = v, sq = v * v;
    #pragma unroll
    for (int off = 32; off; off >>= 1) {
        s  += __shfl_xor(s,  off, 64);
        sq += __shfl_xor(sq, off, 64);
    }
    int wid = tid >> 6;
    if ((tid & 63) == 0) { part[wid][0] = s; part[wid][1] = sq; }
    __syncthreads();
    if (tid == 0) {
        float S = part[0][0] + part[1][0], Q = part[0][1] + part[1][1];
        float m = S / 96.f;
        float var = fmaxf(Q / 96.f - m * m, 0.f);
        float st = sqrtf(var + 1e-5f);
        mv[0] = m; mv[1] = st;
        meanA[row] = m; stdA[row] = st;
    }
    __syncthreads();
    float m = mv[0], st = mv[1];
    const bf16 z16 = __float2bfloat16(0.f);
    if (tid < 96) {
        float xv = (v - m) / st * tof(rw[n]) + tof(rb[n]);
        xr[tid] = xv;
        xT[(size_t)row * L2P + tid] = __float2bfloat16(xv);
    } else {
        xT[(size_t)row * L2P + tid] = z16;
    }
    __syncthreads();
    if (tid < 96) {
        float acc = 0.f;
        #pragma unroll
        for (int d = -12; d <= 12; d++) {
            int k = tid + d;
            k = k < 0 ? 0 : (k > 95 ? 95 : k);
            acc += xr[k];
        }
        trend[(size_t)row * L2P + tid] = __float2bfloat16(acc * (1.f / 25.f));
    } else {
        trend[(size_t)row * L2P + tid] = z16;
    }
}

// ---------------------------------------------------------------------------
__global__ void myf_k(const bf16* __restrict__ yf_w, bf16* __restrict__ MyfT)
{
    int idx = blockIdx.x * 256 + threadIdx.x;
    if (idx >= 512 * L2P) return;
    int d = idx >> 7, l = idx & 127;
    const float invs = 0.10206207261596575f;
    float acc = 0.f;
    if (l < 96) {
        for (int f = 0; f < 25; f++) {
            float ang = (float)(f * l) / 48.0f;
            acc += cospif(ang) * tof(yf_w[f * 512 + d]);
            acc -= sinpif(ang) * tof(yf_w[(25 + f) * 512 + d]);
        }
        acc *= invs;
    }
    MyfT[(size_t)d * L2P + l] = __float2bfloat16(acc);
}

__global__ void ceff_k(const bf16* __restrict__ fc4_w, bf16* __restrict__ CeffT)
{
    int idx = blockIdx.x * 256 + threadIdx.x;
    if (idx >= 512 * 64) return;
    int d = idx >> 6, f = idx & 63;
    const float invs = 0.10206207261596575f;
    float acc = 0.f;
    if (f < 49) {
        for (int l = 0; l < 96; l++) {
            float coef;
            if (f == 0)       coef = 1.f;
            else if (f == 48) coef = (l & 1) ? -1.f : 1.f;
            else              coef = 2.f * cospif((float)(f * l) / 48.f);
            acc += coef * tof(fc4_w[l * 512 + d]);
        }
        acc *= invs;
    }
    CeffT[(size_t)d * 64 + f] = __float2bfloat16(acc);
}

// ---------------------------------------------------------------------------
// epilogue: act 0 none,1 relu,2 lrelu,3 gelu,4 noisy-gate,
//           5 bias - freq_gather(n), 6 bias + freq_gather(512+n)
// ---------------------------------------------------------------------------
__device__ __forceinline__ float epi(float v, int n, int m, int N, int act,
                                     const bf16* bias, const float* Res,
                                     const void* ft, const int* kf,
                                     const int* dflag)
{
    if (act >= 5) {
        v += tof(bias[n]);
        int b = m / NV, nv = m - b * NV;
        int gi = (act == 5) ? (kf[b] + n) % KFL : (kf[b] + 512 + n) % KFL;
        size_t gidx = (size_t)gi * NV + nv;
        float fv = (*dflag) ? ((const float*)ft)[gidx] : tof(((const bf16*)ft)[gidx]);
        return (act == 5) ? v - fv : v + fv;
    }
    if (act == 4) {
        float z = -(v + 0.01f);
        float sp = fmaxf(z, 0.f) + log1pf(expf(-fabsf(z)));
        return Res[(size_t)m * N + n] + tof(bias[n]) * (-sp);
    }
    if (bias) v += tof(bias[n]);
    if (Res)  v += Res[(size_t)m * N + n];
    if (act == 1)      v = fmaxf(v, 0.f);
    else if (act == 2) v = (v >= 0.f) ? v : 0.01f * v;
    else if (act == 3) v = 0.5f * v * (1.f + erff(v * 0.70710678118654752f));
    return v;
}

// ---------------------------------------------------------------------------
// 256x256 MFMA GEMM, 1024 threads = 16 waves x 64x64 quadrant (acc[4][4],
// 64 VGPR/thread -> no spill; r10 verified clean). Counted-vmcnt double
// buffer, 128KB LDS (1 blk/CU). ROUTING RULE (r10 lesson): only use for
// shapes whose grid is >=216 blocks or a clean single round -- at 1 blk/CU,
// N=512 shapes give 108 blocks = 42% idle CUs and regress vs gemm64c.
// ---------------------------------------------------------------------------
__global__ __launch_bounds__(1024, 1)
void gemm256(const bf16* __restrict__ A, int lda,
             const bf16* __restrict__ Wt, int ldb,
             const bf16* __restrict__ bias, const float* Res,
             float* C32, bf16* C16, int M, int N, int K, int act, int gx)
{
    __shared__ __align__(16) bf16 As[2][256 * 64];   // 32 KB x2
    __shared__ __align__(16) bf16 Bs[2][256 * 64];   // 32 KB x2
    int tid = threadIdx.x;
    int w = tid >> 6, lane = tid & 63;
    int lr = lane >> 4, lc = lane & 15;
    int nid = xcd_swz(blockIdx.x, gridDim.x);
    int bx = nid % gx, by = nid / gx;
    int row0 = by * 256, col0 = bx * 256;
    int mq = (w >> 2) * 64;      // 4 row-quadrants
    int nq = (w & 3) * 64;       // 4 col-quadrants
    f4v acc[4][4] = {};
    int nt = K >> 6;
    stage256k(A, lda, row0, M - 1, 0, As[0], tid);
    stage256k(Wt, ldb, col0, N - 1, 0, Bs[0], tid);
    if (nt > 1) {
        stage256k(A, lda, row0, M - 1, 64, As[1], tid);
        stage256k(Wt, ldb, col0, N - 1, 64, Bs[1], tid);
        VMW4();
    } else {
        VMW0();
    }
    BAR(); SCB();
    for (int t = 0; t < nt; t++) {
        int cur = t & 1;
        #pragma unroll
        for (int sub = 0; sub < 2; sub++) {
            int ck = sub * 4 + lr;
            s8v a[4], b[4];
            #pragma unroll
            for (int mt = 0; mt < 4; mt++) a[mt] = *(const s8v*)&As[cur][sxl(mq + mt * 16 + lc, ck)];
            #pragma unroll
            for (int j = 0; j < 4; j++) b[j] = *(const s8v*)&Bs[cur][sxl(nq + j * 16 + lc, ck)];
            #pragma unroll
            for (int mt = 0; mt < 4; mt++)
                #pragma unroll
                for (int j = 0; j < 4; j++)
                    acc[mt][j] = __builtin_amdgcn_mfma_f32_16x16x32_bf16(a[mt], b[j], acc[mt][j], 0, 0, 0);
        }
        if (t + 1 < nt) {
            SCB(); BAR(); SCB();        // all waves done reading buf[cur]
            if (t + 2 < nt) {
                stage256k(A, lda, row0, M - 1, (t + 2) << 6, As[cur], tid);
                stage256k(Wt, ldb, col0, N - 1, (t + 2) << 6, Bs[cur], tid);
                VMW4();                 // t+1's loads complete; t+2's stay in flight
            } else {
                VMW0();
            }
            BAR(); SCB();
        }
    }
    #pragma unroll
    for (int mt = 0; mt < 4; mt++)
    #pragma unroll
    for (int j = 0; j < 4; j++) {
        #pragma unroll
        for (int r = 0; r < 4; r++) {
            int m = row0 + mq + mt * 16 + lr * 4 + r;
            int n = col0 + nq + j * 16 + lc;
            if (m >= M || n >= N) continue;
            float v = epi(acc[mt][j][r], n, m, N, act, bias, Res, nullptr, nullptr, nullptr);
            if (C32) C32[(size_t)m * N + n] = v;
            if (C16) C16[(size_t)m * N + n] = __float2bfloat16(v);
        }
    }
}

// ---------------------------------------------------------------------------
// counted-vmcnt pipelined 128x128 GEMM (r4 form, best-known for these shapes)
// ---------------------------------------------------------------------------
__global__ __launch_bounds__(256)
void gemm128c(const bf16* __restrict__ A, int lda,
              const bf16* __restrict__ Wt, int ldb,
              const bf16* __restrict__ bias, const float* Res,
              float* C32, bf16* C16, int M, int N, int K, int act, int gx)
{
    __shared__ __align__(16) bf16 As[2][128 * 64];
    __shared__ __align__(16) bf16 Bs[2][128 * 64];
    int tid = threadIdx.x;
    int w = tid >> 6, lane = tid & 63;
    int lr = lane >> 4, lc = lane & 15;
    int nid = xcd_swz(blockIdx.x, gridDim.x);
    int bx = nid % gx, by = nid / gx;
    int row0 = by * 128, col0 = bx * 128;
    int mq = (w >> 1) * 64, nq = (w & 1) * 64;
    f4v acc[4][4] = {};
    int nt = K >> 6;
    stage128(A, lda, row0, M - 1, 0, As[0], tid);
    stage128(Wt, ldb, col0, N - 1, 0, Bs[0], tid);
    if (nt > 1) {
        stage128(A, lda, row0, M - 1, 64, As[1], tid);
        stage128(Wt, ldb, col0, N - 1, 64, Bs[1], tid);
        VMW8();
    } else {
        VMW0();
    }
    BAR(); SCB();
    for (int t = 0; t < nt; t++) {
        int cur = t & 1;
        #pragma unroll
        for (int sub = 0; sub < 2; sub++) {
            int ck = sub * 4 + lr;
            s8v a[4], b[4];
            #pragma unroll
            for (int mt = 0; mt < 4; mt++) a[mt] = *(const s8v*)&As[cur][sxl(mq + mt * 16 + lc, ck)];
            #pragma unroll
            for (int j = 0; j < 4; j++) b[j] = *(const s8v*)&Bs[cur][sxl(nq + j * 16 + lc, ck)];
            #pragma unroll
            for (int mt = 0; mt < 4; mt++)
                #pragma unroll
                for (int j = 0; j < 4; j++)
                    acc[mt][j] = __builtin_amdgcn_mfma_f32_16x16x32_bf16(a[mt], b[j], acc[mt][j], 0, 0, 0);
        }
        if (t + 1 < nt) {
            SCB(); BAR(); SCB();
            if (t + 2 < nt) {
                stage128(A, lda, row0, M - 1, (t + 2) << 6, As[cur], tid);
                stage128(Wt, ldb, col0, N - 1, (t + 2) << 6, Bs[cur], tid);
                VMW8();
            } else {
                VMW0();
            }
            BAR(); SCB();
        }
    }
    #pragma unroll
    for (int mt = 0; mt < 4; mt++)
    #pragma unroll
    for (int j = 0; j < 4; j++) {
        #pragma unroll
        for (int r = 0; r < 4; r++) {
            int m = row0 + mq + mt * 16 + lr * 4 + r;
            int n = col0 + nq + j * 16 + lc;
            if (m >= M || n >= N) continue;
            float v = epi(acc[mt][j][r], n, m, N, act, bias, Res, nullptr, nullptr, nullptr);
            if (C32) C32[(size_t)m * N + n] = v;
            if (C16) C16[(size_t)m * N + n] = __float2bfloat16(v);
        }
    }
}

// ---------------------------------------------------------------------------
// counted-vmcnt pipelined 64x128 GEMM (r4 form)
// ---------------------------------------------------------------------------
__global__ __launch_bounds__(256)
void gemm64c(const bf16* __restrict__ A, int lda,
             const bf16* __restrict__ Wt, int ldb,
             const bf16* __restrict__ bias, const float* Res,
             float* C32, bf16* C16, int M, int N, int K, int act,
             const void* ft, const int* kf, const int* dflag, int gx)
{
    __shared__ __align__(16) bf16 As[2][64 * 64];
    __shared__ __align__(16) bf16 Bs[2][128 * 64];
    int tid = threadIdx.x;
    int w = tid >> 6, lane = tid & 63;
    int lr = lane >> 4, lc = lane & 15;
    int nid = xcd_swz(blockIdx.x, gridDim.x);
    int bx = nid % gx, by = nid / gx;
    int row0 = by * 64, col0 = bx * 128;
    int mq = (w >> 1) * 32, nq = (w & 1) * 64;
    f4v acc[2][4] = {};
    int nt = K >> 6;
    stage64(A, lda, row0, M - 1, 0, As[0], tid);
    stage128(Wt, ldb, col0, N - 1, 0, Bs[0], tid);
    if (nt > 1) {
        stage64(A, lda, row0, M - 1, 64, As[1], tid);
        stage128(Wt, ldb, col0, N - 1, 64, Bs[1], tid);
        VMW6();
    } else {
        VMW0();
    }
    BAR(); SCB();
    for (int t = 0; t < nt; t++) {
        int cur = t & 1;
        #pragma unroll
        for (int sub = 0; sub < 2; sub++) {
            int ck = sub * 4 + lr;
            s8v a[2], b[4];
            #pragma unroll
            for (int mt = 0; mt < 2; mt++) a[mt] = *(const s8v*)&As[cur][sxl(mq + mt * 16 + lc, ck)];
            #pragma unroll
            for (int j = 0; j < 4; j++) b[j] = *(const s8v*)&Bs[cur][sxl(nq + j * 16 + lc, ck)];
            #pragma unroll
            for (int mt = 0; mt < 2; mt++)
                #pragma unroll
                for (int j = 0; j < 4; j++)
                    acc[mt][j] = __builtin_amdgcn_mfma_f32_16x16x32_bf16(a[mt], b[j], acc[mt][j], 0, 0, 0);
        }
        if (t + 1 < nt) {
            SCB(); BAR(); SCB();
            if (t + 2 < nt) {
                stage64(A, lda, row0, M - 1, (t + 2) << 6, As[cur], tid);
                stage128(Wt, ldb, col0, N - 1, (t + 2) << 6, Bs[cur], tid);
                VMW6();
            } else {
                VMW0();
            }
            BAR(); SCB();
        }
    }
    #pragma unroll
    for (int mt = 0; mt < 2; mt++)
    #pragma unroll
    for (int j = 0; j < 4; j++) {
        #pragma unroll
        for (int r = 0; r < 4; r++) {
            int m = row0 + mq + mt * 16 + lr * 4 + r;
            int n = col0 + nq + j * 16 + lc;
            if (m >= M || n >= N) continue;
            float v = epi(acc[mt][j][r], n, m, N, act, bias, Res, ft, kf, dflag);
            if (C32) C32[(size_t)m * N + n] = v;
            if (C16) C16[(size_t)m * N + n] = __float2bfloat16(v);
        }
    }
}

// ---------------------------------------------------------------------------
// merged output GEMMs (counted pipeline, r4 form): z in {0:dec, 1:x_time, 2:x_fre}
// ---------------------------------------------------------------------------
__global__ __launch_bounds__(256)
void outg_mfma(const bf16* __restrict__ xb16, const bf16* __restrict__ xfre16,
               const bf16* __restrict__ fcoT, const bf16* __restrict__ fc3T,
               const bf16* __restrict__ fc5T, const bf16* __restrict__ fcob,
               const bf16* __restrict__ fc3b, const bf16* __restrict__ fc5b,
               const bf16* __restrict__ rw, const bf16* __restrict__ rb,
               const float* __restrict__ meanA, const float* __restrict__ stdA,
               void* __restrict__ outv, const int* __restrict__ flag)
{
    __shared__ __align__(16) bf16 As[2][64 * 64];
    __shared__ __align__(16) bf16 Bs[2][64 * 64];
    const int M = NBN, N = 96;
    const size_t OSZ = (size_t)B_ * L_ * NV;
    int z = blockIdx.z;
    const bf16 *A1, *W1, *A2 = nullptr, *W2 = nullptr, *bias;
    int ldb; size_t obase;
    if (z == 0) { A1 = xb16; W1 = fcoT; A2 = xfre16; W2 = fcoT + 512; ldb = 1024; bias = fcob; obase = 0; }
    else if (z == 1) { A1 = xb16; W1 = fc3T; ldb = 512; bias = fc3b; obase = OSZ; }
    else { A1 = xfre16; W1 = fc5T; ldb = 512; bias = fc5b; obase = 2 * OSZ; }
    int tid = threadIdx.x;
    int w = tid >> 6, lane = tid & 63;
    int lr = lane >> 4, lc = lane & 15;
    int row0 = blockIdx.y * 64, col0 = blockIdx.x * 64;
    int mq = (w >> 1) * 32, nq = (w & 1) * 32;
    int f32o = *flag;
    f4v acc[2][2] = {};
    int nt = (z == 0) ? 16 : 8;       // 8 K-steps per 512-wide part
    stage64(A1, 512, row0, M - 1, 0, As[0], tid);
    stage64(W1, ldb, col0, N - 1, 0, Bs[0], tid);
    stage64(A1, 512, row0, M - 1, 64, As[1], tid);
    stage64(W1, ldb, col0, N - 1, 64, Bs[1], tid);
    VMW4();
    BAR(); SCB();
    for (int t = 0; t < nt; t++) {
        int cur = t & 1;
        #pragma unroll
        for (int sub = 0; sub < 2; sub++) {
            int ck = sub * 4 + lr;
            s8v a0 = *(const s8v*)&As[cur][sxl(mq + lc, ck)];
            s8v a1 = *(const s8v*)&As[cur][sxl(mq + 16 + lc, ck)];
            s8v b0 = *(const s8v*)&Bs[cur][sxl(nq + lc, ck)];
            s8v b1 = *(const s8v*)&Bs[cur][sxl(nq + 16 + lc, ck)];
            acc[0][0] = __builtin_amdgcn_mfma_f32_16x16x32_bf16(a0, b0, acc[0][0], 0, 0, 0);
            acc[0][1] = __builtin_amdgcn_mfma_f32_16x16x32_bf16(a0, b1, acc[0][1], 0, 0, 0);
            acc[1][0] = __builtin_amdgcn_mfma_f32_16x16x32_bf16(a1, b0, acc[1][0], 0, 0, 0);
            acc[1][1] = __builtin_amdgcn_mfma_f32_16x16x32_bf16(a1, b1, acc[1][1], 0, 0, 0);
        }
        if (t + 1 < nt) {
            SCB(); BAR(); SCB();
            if (t + 2 < nt) {
                int tn = t + 2;
                const bf16* Ax = (z == 0 && tn >= 8) ? A2 : A1;
                const bf16* Wx = (z == 0 && tn >= 8) ? W2 : W1;
                stage64(Ax, 512, row0, M - 1, (tn & 7) << 6, As[cur], tid);
                stage64(Wx, ldb, col0, N - 1, (tn & 7) << 6, Bs[cur], tid);
                VMW4();
            } else {
                VMW0();
            }
            BAR(); SCB();
        }
    }
    #pragma unroll
    for (int mt = 0; mt < 2; mt++)
    #pragma unroll
    for (int j = 0; j < 2; j++) {
        #pragma unroll
        for (int r = 0; r < 4; r++) {
            int m = row0 + mq + mt * 16 + lr * 4 + r;
            int c = col0 + nq + j * 16 + lc;
            if (m >= M || c >= N) continue;
            int b = m / NV, n = m - b * NV;
            float v = acc[mt][j][r] + tof(bias[c]);
            v = (v - tof(rb[n])) / (tof(rw[n]) + 1e-10f) * stdA[m] + meanA[m];
            size_t oidx = obase + ((size_t)b * L_ + c) * NV + n;
            if (f32o) ((float*)outv)[oidx] = v;
            else      ((bf16*)outv)[oidx] = __float2bfloat16(v);
        }
    }
}

// ---------------------------------------------------------------------------
// Gating -> 64-bit mask words (xe cached in registers: one global read pass)
// ---------------------------------------------------------------------------
__global__ __launch_bounds__(256)
void gating_k(const float* __restrict__ xe, u64* __restrict__ mask64)
{
    int row = blockIdx.x;
    int i = row % NV;
    int tid = threadIdx.x;
    size_t base = (size_t)row * NV;
    float vals[4];
    int cnt = 0;
    float mn = INFINITY, mx = -INFINITY;
    for (int j = tid; j < NV; j += 256) {
        float e = xe[base + j];
        vals[cnt++] = e;
        mn = fminf(mn, e);
        mx = fmaxf(mx, e);
    }
    #pragma unroll
    for (int off = 32; off; off >>= 1) {
        mn = fminf(mn, __shfl_xor(mn, off, 64));
        mx = fmaxf(mx, __shfl_xor(mx, off, 64));
    }
    __shared__ float smn[4], smx[4], fin[2];
    int w = tid >> 6, lane = tid & 63;
    if (lane == 0) { smn[w] = mn; smx[w] = mx; }
    __syncthreads();
    if (tid == 0) {
        float a = fminf(fminf(smn[0], smn[1]), fminf(smn[2], smn[3]));
        float c = fmaxf(fmaxf(smx[0], smx[1]), fmaxf(smx[2], smx[3]));
        fin[0] = a;
        fin[1] = 1.f / (c - a + 1e-6f);
    }
    __syncthreads();
    float a = fin[0], inv = fin[1];
    cnt = 0;
    for (int t = w; t < 14; t += 4) {
        int j = t * 64 + lane;            // == tid + 256*cnt
        bool masked = true;
        if (j < NV) {
            float lg = (vals[cnt++] - a) * inv + ((j == i) ? 1.f : 0.f);
            masked = (lg < 0.5f);
        }
        u64 word = __ballot(masked);
        if (lane == 0) mask64[(size_t)row * 16 + t] = word;
    }
}

// ---------------------------------------------------------------------------
__global__ __launch_bounds__(256)
void ln_k(const float* __restrict__ X, const bf16* __restrict__ g,
          const bf16* __restrict__ bta, float* __restrict__ Y32,
          bf16* __restrict__ Y16)
{
    int row = blockIdx.x;
    int tid = threadIdx.x;
    size_t base = (size_t)row * DM;
    float v0 = X[base + tid], v1 = X[base + tid + 256];
    float s = v0 + v1, sq = v0 * v0 + v1 * v1;
    #pragma unroll
    for (int off = 32; off; off >>= 1) {
        s  += __shfl_xor(s,  off, 64);
        sq += __shfl_xor(sq, off, 64);
    }
    __shared__ float ps[4], pq[4], mv[2];
    int wid = tid >> 6;
    if ((tid & 63) == 0) { ps[wid] = s; pq[wid] = sq; }
    __syncthreads();
    if (tid == 0) {
        float S = ps[0] + ps[1] + ps[2] + ps[3];
        float Q = pq[0] + pq[1] + pq[2] + pq[3];
        float m = S / 512.f;
        float var = fmaxf(Q / 512.f - m * m, 0.f);
        mv[0] = m;
        mv[1] = rsqrtf(var + 1e-5f);
    }
    __syncthreads();
    float m = mv[0], r = mv[1];
    float o0 = (v0 - m) * r * tof(g[tid])       + tof(bta[tid]);
    float o1 = (v1 - m) * r * tof(g[tid + 256]) + tof(bta[tid + 256]);
    if (Y32) { Y32[base + tid] = o0; Y32[base + tid + 256] = o1; }
    if (Y16) { Y16[base + tid] = __float2bfloat16(o0);
               Y16[base + tid + 256] = __float2bfloat16(o1); }
}

// ---------------------------------------------------------------------------
// Double LayerNorm (layer-2 second LN fused with final norm): z=LN(LN(x)g1+b1)g2+b2
// ---------------------------------------------------------------------------
__global__ __launch_bounds__(256)
void ln2x_k(const float* __restrict__ X, const bf16* __restrict__ g1,
            const bf16* __restrict__ b1, const bf16* __restrict__ g2,
            const bf16* __restrict__ b2, bf16* __restrict__ Y16)
{
    int row = blockIdx.x;
    int tid = threadIdx.x;
    size_t base = (size_t)row * DM;
    float v0 = X[base + tid], v1 = X[base + tid + 256];
    __shared__ float ps[4], pq[4], mv[2];
    int wid = tid >> 6;
    // pass 1
    {
        float s = v0 + v1, sq = v0 * v0 + v1 * v1;
        #pragma unroll
        for (int off = 32; off; off >>= 1) {
            s  += __shfl_xor(s,  off, 64);
            sq += __shfl_xor(sq, off, 64);
        }
        if ((tid & 63) == 0) { ps[wid] = s; pq[wid] = sq; }
        __syncthreads();
        if (tid == 0) {
            float S = ps[0] + ps[1] + ps[2] + ps[3];
            float Q = pq[0] + pq[1] + pq[2] + pq[3];
            float m = S / 512.f;
            float var = fmaxf(Q / 512.f - m * m, 0.f);
            mv[0] = m; mv[1] = rsqrtf(var + 1e-5f);
        }
        __syncthreads();
    }
    float m1 = mv[0], r1 = mv[1];
    float y0 = (v0 - m1) * r1 * tof(g1[tid])       + tof(b1[tid]);
    float y1 = (v1 - m1) * r1 * tof(g1[tid + 256]) + tof(b1[tid + 256]);
    __syncthreads();
    // pass 2
    {
        float s = y0 + y1, sq = y0 * y0 + y1 * y1;
        #pragma unroll
        for (int off = 32; off; off >>= 1) {
            s  += __shfl_xor(s,  off, 64);
            sq += __shfl_xor(sq, off, 64);
        }
        if ((tid & 63) == 0) { ps[wid] = s; pq[wid] = sq; }
        __syncthreads();
        if (tid == 0) {
            float S = ps[0] + ps[1] + ps[2] + ps[3];
            float Q = pq[0] + pq[1] + pq[2] + pq[3];
            float m = S / 512.f;
            float var = fmaxf(Q / 512.f - m * m, 0.f);
            mv[0] = m; mv[1] = rsqrtf(var + 1e-5f);
        }
        __syncthreads();
    }
    float m2 = mv[0], r2 = mv[1];
    Y16[base + tid]       = __float2bfloat16((y0 - m2) * r2 * tof(g2[tid])       + tof(b2[tid]));
    Y16[base + tid + 256] = __float2bfloat16((y1 - m2) * r2 * tof(g2[tid + 256]) + tof(b2[tid + 256]));
}

// ---------------------------------------------------------------------------
// Flash MFMA attention v7 (r4 form): LDS-staged K/V via global_load_lds +
// counted-vmcnt double buffer, conflict-free stride-64 layout, px/pxc P-tile.
// ---------------------------------------------------------------------------
__global__ __launch_bounds__(256)
void attn_k(const bf16* __restrict__ qkv, const bf16* __restrict__ Vt,
            const u64* __restrict__ mask64, bf16* __restrict__ O)
{
    __shared__ __align__(16) bf16 Ks[2][64 * 64];
    __shared__ __align__(16) bf16 Vs[2][64 * 64];
    __shared__ bf16 Pt[4][16 * 64];
    int bid = blockIdx.x;
    int bh = bid & 127;                 // B*NH = 128, fastest -> same XCD per (b,h)
    int q0 = (bid >> 7) * 64;
    int b = bh >> 3, h = bh & 7;
    int tid = threadIdx.x;
    int w = tid >> 6, lane = tid & 63;
    int lr = lane >> 4, lc = lane & 15;
    size_t hb = (size_t)h * DH;
    int qw = q0 + w * 16;
    const float C = 0.18033688011112042f;   // 0.125 * log2(e)

    s8v qf[2];
    #pragma unroll
    for (int sub = 0; sub < 2; sub++) {
        int gq = qw + lc;
        uint4 v = make_uint4(0, 0, 0, 0);
        if (gq < NV)
            v = *(const uint4*)(qkv + ((size_t)(b * NV + gq)) * QKVW + hb + sub * 32 + lr * 8);
        qf[sub] = *(s8v*)&v;
    }

    const bf16* kbase = qkv + (size_t)b * NV * QKVW + 512 + hb;  // row = key, 64 cols
    const bf16* vbase = Vt + (size_t)bh * DH * NVP;              // row = d, NVP cols

    float lsum[4] = {0.f, 0.f, 0.f, 0.f};
    f4v oacc[4] = {};
    const int NT = 14;

    // prologue: stage tiles 0 and 1 (4 VMEM/wave each)
    stage64(kbase, QKVW, 0, NV - 1, 0, Ks[0], tid);
    stage64(vbase, NVP, 0, DH - 1, 0, Vs[0], tid);
    stage64(kbase, QKVW, 64, NV - 1, 0, Ks[1], tid);
    stage64(vbase, NVP, 0, DH - 1, 64, Vs[1], tid);
    VMW4();                             // tile 0 complete; tile 1 in flight
    BAR(); SCB();

    for (int t = 0; t < NT; t++) {
        int cur = t & 1;
        // ---- QK^T from LDS (conflict-free sxl layout) ----
        f4v s[4];
        __builtin_amdgcn_s_setprio(1);
        #pragma unroll
        for (int nt = 0; nt < 4; nt++) {
            f4v sacc = {0.f, 0.f, 0.f, 0.f};
            #pragma unroll
            for (int sub = 0; sub < 2; sub++) {
                s8v bb = *(const s8v*)&Ks[cur][sxl(nt * 16 + lc, sub * 4 + lr)];
                sacc = __builtin_amdgcn_mfma_f32_16x16x32_bf16(qf[sub], bb, sacc, 0, 0, 0);
            }
            s[nt] = sacc;
        }
        __builtin_amdgcn_s_setprio(0);
        // ---- P = exp2(s*C), masked via per-row global mask word ----
        #pragma unroll
        for (int r = 0; r < 4; r++) {
            int gq = qw + lr * 4 + r;
            u64 wd = (gq < NV) ? mask64[(size_t)(b * NV + gq) * 16 + t] : ~0ull;
            #pragma unroll
            for (int nt = 0; nt < 4; nt++) {
                float p = ((wd >> (nt * 16 + lc)) & 1) ? 0.f : exp2f(s[nt][r] * C);
                Pt[w][px(lr * 4 + r, nt * 16 + lc)] = __float2bfloat16(p);
                lsum[r] += p;
            }
        }
        // ---- P @ V from LDS (Pt wave-private, RAW via lgkmcnt) ----
        #pragma unroll
        for (int sub = 0; sub < 2; sub++) {
            s8v pa = *(const s8v*)&Pt[w][pxc(lc, sub * 4 + lr)];
            __builtin_amdgcn_s_setprio(1);
            #pragma unroll
            for (int dt = 0; dt < 4; dt++) {
                s8v vv = *(const s8v*)&Vs[cur][sxl(dt * 16 + lc, sub * 4 + lr)];
                oacc[dt] = __builtin_amdgcn_mfma_f32_16x16x32_bf16(pa, vv, oacc[dt], 0, 0, 0);
            }
            __builtin_amdgcn_s_setprio(0);
        }
        if (t + 1 < NT) {
            SCB(); BAR(); SCB();        // all waves done reading buf[cur]
            if (t + 2 < NT) {
                int j2 = (t + 2) * 64;
                stage64(kbase, QKVW, j2, NV - 1, 0, Ks[cur], tid);
                stage64(vbase, NVP, 0, DH - 1, j2, Vs[cur], tid);
                VMW4();                 // t+1 complete; t+2 in flight
            } else {
                VMW0();
            }
            BAR(); SCB();
        }
    }
    // one deferred row-sum reduction over the 16 lanes sharing each row
    #pragma unroll
    for (int r = 0; r < 4; r++) {
        #pragma unroll
        for (int o2 = 1; o2 < 16; o2 <<= 1) lsum[r] += __shfl_xor(lsum[r], o2, 64);
    }
    #pragma unroll
    for (int r = 0; r < 4; r++) {
        int gq = qw + lr * 4 + r;
        if (gq >= NV) continue;
        float linv = 1.f / fmaxf(lsum[r], 1e-30f);
        #pragma unroll
        for (int dt = 0; dt < 4; dt++)
            O[((size_t)(b * NV + gq)) * DM + hb + dt * 16 + lc] =
                __float2bfloat16(oacc[dt][r] * linv);
    }
}

// ---------------------------------------------------------------------------
static void G256(hipStream_t s, const bf16* A, int lda, const bf16* Wt, int ldb,
                 const bf16* bias, const float* Res, float* C32, bf16* C16,
                 int M, int N, int K, int act)
{
    int gx = (N + 255) / 256, gy = (M + 255) / 256;
    gemm256<<<dim3(gx * gy), 1024, 0, s>>>(A, lda, Wt, ldb, bias, Res, C32, C16,
                                           M, N, K, act, gx);
}
static void G1(hipStream_t s, const bf16* A, int lda, const bf16* Wt, int ldb,
               const bf16* bias, const float* Res, float* C32, bf16* C16,
               int M, int N, int K, int act)
{
    int gx = (N + 127) / 128, gy = (M + 127) / 128;
    gemm128c<<<dim3(gx * gy), 256, 0, s>>>(A, lda, Wt, ldb, bias, Res, C32, C16, M, N, K, act, gx);
}
static void G64(hipStream_t s, const bf16* A, int lda, const bf16* Wt, int ldb,
                const bf16* bias, const float* Res, float* C32, bf16* C16,
                int M, int N, int K, int act,
                const void* ft = nullptr, const int* kf = nullptr, const int* df = nullptr)
{
    int gx = (N + 127) / 128, gy = (M + 63) / 64;
    gemm64c<<<dim3(gx * gy), 256, 0, s>>>(A, lda, Wt, ldb, bias, Res, C32, C16, M, N, K, act, ft, kf, df, gx);
}

enum { I_XENC = 0, I_GNOISE, I_RW, I_RB, I_FC2W, I_FC2B, I_FC3W, I_FC3B,
       I_FC4W, I_FC4B, I_FC5W, I_FC5B, I_TCW1, I_TCW2, I_TNW1, I_TNW2,
       I_LTW1, I_LTB1, I_LTW2, I_LTB2, I_YFW, I_YFB, I_LSW1, I_LSB1,
       I_LSW2, I_LSB2, I_FCOW, I_FCOB, I_FT, I_EWQ, I_EBQ, I_EWK, I_EBK,
       I_EWV, I_EBV, I_EWO, I_EBO, I_C1W, I_C1B, I_C2W, I_C2B,
       I_G1, I_BE1, I_G2, I_BE2, I_NG, I_NB };

extern "C" void kernel_launch(void* const* d_in, const int* in_sizes, int n_in,
                              void* d_out, int out_size, void* d_ws, size_t ws_size,
                              hipStream_t stream)
{
    const int* bkey = (const int*)d_in[47];
    (void)ws_size; (void)in_sizes; (void)n_in; (void)out_size;

    // ---- arena (~190 MB) ----
    float* ws = (float*)d_ws;
    size_t off = 0;
    auto alloc = [&](size_t nf) { nf = (nf + 3) & ~(size_t)3; float* p = ws + off; off += nf; return p; };
    auto balloc = [&](size_t nb) { return (bf16*)alloc((nb + 1) / 2); };
    int*  flag  = (int*)alloc(16);
    bf16* gnoise = balloc(862); bf16* rw = balloc(862); bf16* rb = balloc(862);
    bf16* fc2b = balloc(512);  bf16* fc3b = balloc(96);
    bf16* fc4w_c = balloc(49152); bf16* fc4b = balloc(512); bf16* fc5b = balloc(96);
    bf16* ltb1 = balloc(512);  bf16* ltb2 = balloc(512);
    bf16* yfw_c = balloc(25600); bf16* yfb = balloc(512);
    bf16* lsb1 = balloc(512);  bf16* lsb2 = balloc(512);
    bf16* fcob = balloc(96);
    bf16* qkvb = balloc(2 * QKVW);
    bf16* ebo = balloc(1024);  bf16* c1b = balloc(2048); bf16* c2b = balloc(1024);
    bf16* g1v = balloc(1024);  bf16* be1v = balloc(1024);
    bf16* g2v = balloc(1024);  bf16* be2v = balloc(1024);
    bf16* ngv = balloc(512);   bf16* nbv = balloc(512);
    bf16* fc2wT = balloc(512 * L2P);  bf16* fc3wT = balloc(49152); bf16* fc5wT = balloc(49152);
    bf16* lt1T = balloc(512 * L2P);   bf16* lt2T = balloc(262144);
    bf16* ls1T = balloc(262144);  bf16* ls2T = balloc(262144);
    bf16* fcoT = balloc(98304);
    bf16* tc2T = balloc(220672);  bf16* tn2T = balloc(220672);
    bf16* gate1w = balloc(262144);
    bf16* qkvw = balloc(2 * QKVW * 512);
    bf16* woT = balloc(524288);
    bf16* c1T = balloc(1048576);  bf16* c2T = balloc(1048576);
    bf16* xT    = balloc((size_t)NBN * L2P);
    bf16* trend = balloc((size_t)NBN * L2P);
    float* meanA = alloc(13824);
    float* stdA  = alloc(13824);
    bf16* MyfT  = balloc(512 * L2P);
    bf16* CeffT = balloc(512 * 64);
    bf16* y49   = balloc((size_t)NBN * 64);
    float* xb32 = alloc((size_t)NBN * 512);
    bf16* xb16  = balloc((size_t)NBN * 512);
    bf16* xfre16 = balloc((size_t)NBN * 512);
    bf16* tmp16 = balloc((size_t)NBN * 1024);   // FF hidden / gate1 / Vt / freq scratch
    float* fbuf = alloc((size_t)NBN * 512);
    float* gbuf = alloc((size_t)NBN * 1024);    // xe fp32 / yA / qkv16+O16
    u64* mask64 = (u64*)alloc((size_t)NBN * 32);

    float* xe = gbuf;
    bf16* yA  = (bf16*)gbuf;
    bf16* qkv16 = (bf16*)gbuf;                  // [NBN][1536]
    bf16* O16 = qkv16 + (size_t)NBN * QKVW;     // [NBN][512]
    bf16* Vt  = tmp16;                          // [128][64][896]

    detect_k<<<1, 64, 0, stream>>>((const unsigned short*)d_in[I_RW], flag);

    // ---- batched flat conversions ----
    {
        CB cb;
        int k = 0;
        auto add = [&](int idx, bf16* dst, int n, int so) {
            cb.src[k] = d_in[idx]; cb.dst[k] = dst; cb.n[k] = n; cb.so[k] = so; k++;
        };
        add(I_GNOISE, gnoise, 862, 0); add(I_RW, rw, 862, 0); add(I_RB, rb, 862, 0);
        add(I_FC2B, fc2b, 512, 0); add(I_FC3B, fc3b, 96, 0);
        add(I_FC4W, fc4w_c, 49152, 0); add(I_FC4B, fc4b, 512, 0); add(I_FC5B, fc5b, 96, 0);
        add(I_LTB1, ltb1, 512, 0); add(I_LTB2, ltb2, 512, 0);
        add(I_YFW, yfw_c, 25600, 0); add(I_YFB, yfb, 512, 0);
        add(I_LSB1, lsb1, 512, 0); add(I_LSB2, lsb2, 512, 0);
        add(I_FCOB, fcob, 96, 0);
        add(I_EBQ, qkvb + 0, 512, 0);          add(I_EBQ, qkvb + QKVW, 512, 512);
        add(I_EBK, qkvb + 512, 512, 0);        add(I_EBK, qkvb + QKVW + 512, 512, 512);
        add(I_EBV, qkvb + 1024, 512, 0);       add(I_EBV, qkvb + QKVW + 1024, 512, 512);
        add(I_EBO, ebo, 1024, 0); add(I_C1B, c1b, 2048, 0); add(I_C2B, c2b, 1024, 0);
        add(I_G1, g1v, 1024, 0); add(I_BE1, be1v, 1024, 0);
        add(I_G2, g2v, 1024, 0); add(I_BE2, be2v, 1024, 0);
        add(I_NG, ngv, 512, 0); add(I_NB, nbv, 512, 0);
        cvtb_k<<<dim3(192, 30), 256, 0, stream>>>(cb, flag);
    }

    // ---- batched weight transposes (24 entries, one launch; Kp-padded) ----
    {
        WTB wb;
        int k = 0;
        auto add = [&](int idx, bf16* dst, int K, int Kp, int N, long soff) {
            wb.d[k].src = d_in[idx]; wb.d[k].dst = dst;
            wb.d[k].K = K; wb.d[k].Kp = Kp; wb.d[k].N = N; wb.d[k].srcOff = soff; k++;
        };
        add(I_FC2W, fc2wT, 96, L2P, 512, 0);
        add(I_FC3W, fc3wT, 512, 512, 96, 0);
        add(I_FC5W, fc5wT, 512, 512, 96, 0);
        add(I_LTW1, lt1T, 96, L2P, 512, 0);
        add(I_LTW2, lt2T, 512, 512, 512, 0);
        add(I_LSW1, ls1T, 512, 512, 512, 0);
        add(I_LSW2, ls2T, 512, 512, 512, 0);
        add(I_FCOW, fcoT, 1024, 1024, 96, 0);
        add(I_TCW2, tc2T, 256, 256, 862, 0);
        add(I_TNW2, tn2T, 256, 256, 862, 0);
        add(I_TCW1, gate1w, 512, 512, 256, 0);
        add(I_TNW1, gate1w + 256 * 512, 512, 512, 256, 0);
        for (int l = 0; l < 2; l++) {
            add(I_EWO, woT + (size_t)l * 262144, 512, 512, 512, (long)l * 262144);
            add(I_C1W, c1T + (size_t)l * 524288, 512, 512, 1024, (long)l * 524288);
            add(I_C2W, c2T + (size_t)l * 524288, 1024, 1024, 512, (long)l * 524288);
            add(I_EWQ, qkvw + (size_t)l * 786432 + 0,      512, 512, 512, (long)l * 262144);
            add(I_EWK, qkvw + (size_t)l * 786432 + 262144, 512, 512, 512, (long)l * 262144);
            add(I_EWV, qkvw + (size_t)l * 786432 + 524288, 512, 512, 512, (long)l * 262144);
        }
        wtcb_k<<<dim3(32, 32, NWT), 256, 0, stream>>>(wb, flag);
    }

    // ---- RevIN + trend; DFT/IDFT folds ----
    revin_k<<<NBN, 128, 0, stream>>>(d_in[I_XENC], rw, rb, xT, trend, meanA, stdA, flag);
    myf_k<<<(512 * L2P + 255) / 256, 256, 0, stream>>>(yfw_c, MyfT);
    ceff_k<<<(512 * 64 + 255) / 256, 256, 0, stream>>>(fc4w_c, CeffT);

    // ---- frequency branch (all K multiples of 64 via zero-padding; r4 routing) ----
    G64(stream, trend, L2P, lt1T, L2P, ltb1, nullptr, nullptr, tmp16, NBN, 512, L2P, 2);
    G64(stream, tmp16, 512, lt2T, 512, ltb2, nullptr, fbuf, nullptr, NBN, 512, 512, 0); // t
    G64(stream, xT, L2P, MyfT, L2P, yfb, nullptr, nullptr, yA, NBN, 512, L2P, 5,
        d_in[I_FT], bkey, flag);                                         // -freq gather fused
    G64(stream, yA, 512, ls1T, 512, lsb1, nullptr, nullptr, tmp16, NBN, 512, 512, 2);
    G64(stream, tmp16, 512, ls2T, 512, lsb2, nullptr, nullptr, y49, NBN, 64, 512, 6,
        d_in[I_FT], bkey, flag);             // +freq gather fused; cols 49..63 garbage
    G64(stream, y49, 64, CeffT, 64, fc4b, fbuf, nullptr, xfre16, NBN, 512, 64, 0);
                                             // CeffT cols 49..63 are zero -> garbage killed

    // ---- time embedding ----
    G64(stream, xT, L2P, fc2wT, L2P, fc2b, nullptr, xb32, xb16, NBN, 512, L2P, 0);

    // ---- gating -> bitmask (r4 routing) ----
    G64(stream, xb16, 512, gate1w, 512, nullptr, nullptr, nullptr, tmp16, NBN, 512, 512, 1);
    G64(stream, tmp16, 512, tc2T, 256, nullptr, nullptr, xe, nullptr, NBN, 862, 256, 0);
    G64(stream, tmp16 + 256, 512, tn2T, 256, gnoise, xe, xe, nullptr, NBN, 862, 256, 4);
    gating_k<<<NBN, 256, 0, stream>>>(xe, mask64);

    // ---- 2 encoder layers: G256 only for QKV (324 blk) and c1 (216 blk) ----
    for (int l = 0; l < 2; l++) {
        G256(stream, xb16, 512, qkvw + (size_t)l * QKVW * 512, 512,
             qkvb + l * QKVW, nullptr, nullptr, qkv16, NBN, QKVW, 512, 0);
        vt_k<<<dim3(NVP / 32, DH / 32, B_ * NH), 256, 0, stream>>>(qkv16, Vt);
        attn_k<<<dim3(14 * 128), 256, 0, stream>>>(qkv16, Vt, mask64, O16);
        G64(stream, O16, 512, woT + (size_t)l * 262144, 512, ebo + l * 512,
            xb32, fbuf, nullptr, NBN, 512, 512, 0);
        ln_k<<<NBN, 256, 0, stream>>>(fbuf, g1v + l * 512, be1v + l * 512, xb32, xb16);
        G256(stream, xb16, 512, c1T + (size_t)l * 524288, 512, c1b + l * 1024,
             nullptr, nullptr, tmp16, NBN, 1024, 512, 3);
        G64(stream, tmp16, 1024, c2T + (size_t)l * 524288, 1024, c2b + l * 512,
            xb32, fbuf, nullptr, NBN, 512, 1024, 0);
        if (l == 0)
            ln_k<<<NBN, 256, 0, stream>>>(fbuf, g2v, be2v, xb32, xb16);
        else
            ln2x_k<<<NBN, 256, 0, stream>>>(fbuf, g2v + 512, be2v + 512, ngv, nbv, xb16);
    }

    // ---- merged output GEMMs ----
    outg_mfma<<<dim3(2, (NBN + 63) / 64, 3), 256, 0, stream>>>(
        xb16, xfre16, fcoT, fc3wT, fc5wT, fcob, fc3b, fc5b,
        rw, rb, meanA, stdA, d_out, flag);
}